// Round 2
// baseline (931.746 us; speedup 1.0000x reference)
//
#include <hip/hip_runtime.h>
#include <hip/hip_bf16.h>
#include <stdint.h>

#define EDGES 65536

typedef unsigned int uint;
typedef unsigned short ushort;
using bf16x8 = __attribute__((ext_vector_type(8))) __bf16;
using f32x4  = __attribute__((ext_vector_type(4))) float;
using uintx4 = __attribute__((ext_vector_type(4))) uint;

#define C_OLD 0.8944271909999159f
#define C_NEW 0.4472135954999579f
#define T_SCALE 0.08838834764831845f

__device__ __forceinline__ ushort f2bf(float f) {
  uint x = __builtin_bit_cast(uint, f);
  uint r = x + 0x7FFFu + ((x >> 16) & 1u);
  return (ushort)(r >> 16);
}
__device__ __forceinline__ float bf2f(ushort u) {
  uint x = (uint)u << 16;
  return __builtin_bit_cast(float, x);
}

// ---------------- weight pack kernels ----------------
__global__ __launch_bounds__(256) void k_pack_b0(const float* __restrict__ W0, ushort* __restrict__ B) {
  int idx = blockIdx.x * 256 + threadIdx.x;
  if (idx >= 160 * 3200) return;
  int o = idx / 3200, kf = idx - o * 3200;
  int k = kf / 352, f = kf - k * 352;
  float v = (k < 9 && f < 336) ? W0[k * 53760 + f * 160 + o] : 0.f;
  B[idx] = f2bf(v);
}
__global__ __launch_bounds__(256) void k_pack_b1(const float* __restrict__ Wr, const float* __restrict__ Wi, ushort* __restrict__ B) {
  int idx = blockIdx.x * 256 + threadIdx.x;
  if (idx >= 96 * 2624) return;
  int c = idx / 2624, kf = idx - c * 2624;
  int k = kf / 288, f = kf - k * 288;
  float v = 0.f;
  if (k < 9) {
    if (c < 48) v = (f < 144) ? Wr[k * 6912 + f * 48 + c] : -Wi[k * 6912 + (f - 144) * 48 + c];
    else        v = (f < 144) ? Wi[k * 6912 + f * 48 + (c - 48)] : Wr[k * 6912 + (f - 144) * 48 + (c - 48)];
  }
  B[idx] = f2bf(v);
}
__global__ __launch_bounds__(256) void k_pack_b2(const float* __restrict__ Wr, const float* __restrict__ Wi, ushort* __restrict__ B) {
  int idx = blockIdx.x * 256 + threadIdx.x;
  if (idx >= 32 * 896) return;
  int c = idx / 896, kf = idx - c * 896;
  int k = kf / 96, f = kf - k * 96;
  float v = 0.f;
  if (k < 9) {
    if (c < 16) v = (f < 48) ? Wr[k * 768 + f * 16 + c] : -Wi[k * 768 + (f - 48) * 16 + c];
    else        v = (f < 48) ? Wi[k * 768 + f * 16 + (c - 16)] : Wr[k * 768 + (f - 48) * 16 + (c - 16)];
  }
  B[idx] = f2bf(v);
}
__global__ __launch_bounds__(256) void k_pack_w(const float* __restrict__ W, ushort* __restrict__ Wt, int K, int N) {
  int idx = blockIdx.x * 256 + threadIdx.x;
  if (idx >= K * N) return;
  int n = idx / K, k = idx - n * K;
  Wt[idx] = f2bf(W[k * N + n]);
}
__global__ __launch_bounds__(256) void k_pack_we(const float* __restrict__ We, ushort* __restrict__ Wt) {
  int idx = blockIdx.x * 256 + threadIdx.x;
  if (idx >= 128 * 128) return;
  int n = idx >> 7, k = idx & 127;
  float v = (n < 112) ? We[k * 112 + n] : 0.f;
  Wt[idx] = f2bf(v);
}
__global__ __launch_bounds__(256) void k_pack_tt(const float* __restrict__ T0, const float* __restrict__ T1,
                                                 const float* __restrict__ T2, ushort* __restrict__ Wt) {
  int idx = blockIdx.x * 256 + threadIdx.x;
  if (idx >= 128 * 128) return;
  int o = idx >> 7, h = idx & 127;
  float v = 0.f;
  if (o < 64) v = T0[o * 128 + h];
  else if (o < 96) v = T1[(o - 64) * 128 + h];
  else if (o < 112) v = T2[(o - 96) * 128 + h];
  Wt[idx] = f2bf(v);
}

// ---------------- prep: gather + Wigner rotate + softmax gates ----------------
__global__ __launch_bounds__(256) void k_prep(
    const float* __restrict__ node_f, const float* __restrict__ edge_f,
    const float* __restrict__ D1g, const float* __restrict__ D2g,
    const float* __restrict__ mg_g, const float* __restrict__ Wg,
    const float* __restrict__ latg, const float* __restrict__ eohg,
    const int* __restrict__ eidx, const int* __restrict__ act,
    ushort* __restrict__ f_all, float* __restrict__ gf_out,
    ushort* __restrict__ lat_bf, ushort* __restrict__ mlp2_in) {
  __shared__ float sh[4][832];
  const int w = threadIdx.x >> 6, lane = threadIdx.x & 63;
  const int e = blockIdx.x * 4 + w;
  float* s = sh[w];
  float* s_nc = s;
  float* s_ef = s + 240;
  float* s_nn = s + 480;
  float* s_d1 = s + 720;
  float* s_d2 = s + 729;
  float* s_mg = s + 754;
  float* s_lg = s + 818;
  const int ae = act[e];
  const int ec = eidx[ae], en = eidx[EDGES + ae];
  for (int i = lane; i < 240; i += 64) {
    s_nc[i] = node_f[ec * 240 + i];
    s_ef[i] = edge_f[e * 240 + i];
    s_nn[i] = node_f[en * 240 + i];
  }
  if (lane < 9)  s_d1[lane] = D1g[e * 9 + lane];
  if (lane < 25) s_d2[lane] = D2g[e * 25 + lane];
  s_mg[lane] = mg_g[e * 64 + lane];
  for (int i = lane; i < 128; i += 64) {
    lat_bf[e * 128 + i] = f2bf(latg[ae * 128 + i]);
    mlp2_in[e * 256 + 128 + i] = f2bf(eohg[e * 128 + i]);
  }
  __syncthreads();
  if (lane < 8) {
    float a = 0.f;
    for (int h = 0; h < 64; ++h) a += s_mg[h] * Wg[h * 8 + lane];
    s_lg[lane] = a;
  }
  __syncthreads();
  if (lane < 12) {
    float m = s_lg[0];
    for (int j = 1; j < 8; ++j) m = fmaxf(m, s_lg[j]);
    float den = 0.f;
    for (int j = 0; j < 8; ++j) den += __expf(s_lg[j] - m);
    float v = 0.f;
    if (lane < 8) v = __expf(s_lg[lane] - m) / den;
    else if (lane == 8) v = 1.f;
    gf_out[e * 12 + lane] = v;
  }
  auto x1v = [&](int c, int j) -> float {
    if (c < 32) return s_nc[64 + c * 3 + j];
    if (c < 64) return s_ef[64 + (c - 32) * 3 + j];
    return s_nn[64 + (c - 64) * 3 + j];
  };
  auto x2v = [&](int c, int j) -> float {
    if (c < 16) return s_nc[160 + c * 5 + j];
    if (c < 32) return s_ef[160 + (c - 16) * 5 + j];
    return s_nn[160 + (c - 32) * 5 + j];
  };
  auto y1v = [&](int c, int i) -> float {
    float a = 0.f;
    for (int j = 0; j < 3; ++j) a += s_d1[i * 3 + j] * x1v(c, j);
    return a;
  };
  auto y2v = [&](int c, int i) -> float {
    float a = 0.f;
    for (int j = 0; j < 5; ++j) a += s_d2[i * 5 + j] * x2v(c, j);
    return a;
  };
  // f_all layout: [f0 336 | fp1 144 | fm1 144 | fp2 48 | fm2 48]
  for (int idx = lane; idx < 720; idx += 64) {
    float val;
    if (idx < 192) {
      int sidx = idx >> 6, cm = idx & 63;
      val = (sidx == 0) ? s_nc[cm] : (sidx == 1) ? s_ef[cm] : s_nn[cm];
    } else if (idx < 288) val = y1v(idx - 192, 1);
    else if (idx < 336) val = y2v(idx - 288, 2);
    else if (idx < 432) val = y1v(idx - 336, 2);
    else if (idx < 480) val = y2v(idx - 432, 3);
    else if (idx < 576) val = y1v(idx - 480, 0);
    else if (idx < 624) val = y2v(idx - 576, 1);
    else if (idx < 672) val = y2v(idx - 624, 4);
    else                val = y2v(idx - 672, 0);
    f_all[e * 720 + idx] = f2bf(val);
  }
}

// ---------------- generic bf16 MFMA GEMM, optional 9-expert gf-fold, bf16 out ----------------
template <int KZP, int SPG, int NGRP, int NCOL, int FPREAL, int FOFF, int ASTRIDE, int ROWB,
          bool HASBIAS, bool DOSILU>
__global__ __launch_bounds__(256) void k_gemm(
    const ushort* __restrict__ A, const ushort* __restrict__ Bt,
    const float* __restrict__ gf, const float* __restrict__ bias,
    ushort* __restrict__ outb, int ob_stride, int ob_off) {
  constexpr int NF = NCOL / 16;
  constexpr int NFW = NF / 2;
  constexpr int CPR = ROWB / 16;
  constexpr int SMEM = 32 * ROWB + NCOL * 128 + ((NGRP > 1) ? 1536 : 16);
  static_assert(ROWB % 128 == 0 && NF % 2 == 0 && KZP % 64 == 0 && (CPR % 8) == 0, "geom");
  __shared__ uintx4 smem4[SMEM / 16];
  char* sm = (char*)smem4;
  char* f_lds = sm;
  char* b_lds = sm + 32 * ROWB;
  float* gf_lds = (float*)(sm + 32 * ROWB + NCOL * 128);
  const int tid = threadIdx.x;
  const int lane = tid & 63, w = tid >> 6;
  const int wr = w >> 1, wc = w & 1;
  const int e0 = blockIdx.x * 32;
  const f32x4 vzero = {0.f, 0.f, 0.f, 0.f};

#pragma unroll
  for (int it = 0; it < CPR / 8; ++it) {
    int q = tid + it * 256;
    int r = q / CPR, ch = q - r * CPR;
    uintx4 v = {0u, 0u, 0u, 0u};
    if (ch * 8 < FPREAL)
      v = *(const uintx4*)(A + (size_t)(e0 + r) * ASTRIDE + FOFF + ch * 8);
    *(uintx4*)(f_lds + r * ROWB + ((ch * 16) ^ ((r & 7) << 4))) = v;
  }
  if constexpr (NGRP > 1) {
    for (int q = tid; q < 384; q += 256)
      gf_lds[q] = gf[(e0 + q / 12) * 12 + (q - (q / 12) * 12)];
  }
  __syncthreads();

  f32x4 accS[NFW];
#pragma unroll
  for (int n = 0; n < NFW; ++n) accS[n] = vzero;
  f32x4 accC[(NGRP > 1) ? NFW : 1];
  if constexpr (NGRP > 1) {
#pragma unroll
    for (int n = 0; n < NFW; ++n) accC[n] = vzero;
  }
  const int g16 = lane >> 4;
  const int rA = wr * 16 + (lane & 15);
  const int abase = rA * ROWB;
  const int axor = (rA & 7) << 4;

  constexpr int NT2 = KZP / 64;
  for (int t2 = 0; t2 < NT2; ++t2) {
#pragma unroll
    for (int it = 0; it < NCOL / 32; ++it) {
      int q = tid + it * 256;
      int c = q >> 3, ch = q & 7;
      uintx4 v = *(const uintx4*)(Bt + (size_t)c * KZP + t2 * 64 + ch * 8);
      *(uintx4*)(b_lds + c * 128 + ((ch ^ (c & 7)) << 4)) = v;
    }
    __syncthreads();
#pragma unroll
    for (int s = 0; s < 2; ++s) {
      const int t = t2 * 2 + s;
      const int g = t / SPG;
      const int ts = t - g * SPG;
      const int fidx = ts * 32 + g16 * 8;
      bf16x8 a = *(const bf16x8*)(f_lds + abase + ((fidx * 2) ^ axor));
#pragma unroll
      for (int n = 0; n < NFW; ++n) {
        const int cB = (wc * NFW + n) * 16 + (lane & 15);
        const int ch = s * 4 + g16;
        bf16x8 b = *(const bf16x8*)(b_lds + cB * 128 + ((ch ^ (cB & 7)) << 4));
        if constexpr (NGRP > 1)
          accC[n] = __builtin_amdgcn_mfma_f32_16x16x32_bf16(a, b, accC[n], 0, 0, 0);
        else
          accS[n] = __builtin_amdgcn_mfma_f32_16x16x32_bf16(a, b, accS[n], 0, 0, 0);
      }
      if constexpr (NGRP > 1) {
        if (ts == SPG - 1 && g < NGRP) {
          float g4[4];
#pragma unroll
          for (int j = 0; j < 4; ++j)
            g4[j] = gf_lds[(wr * 16 + g16 * 4 + j) * 12 + g];
#pragma unroll
          for (int n = 0; n < NFW; ++n) {
#pragma unroll
            for (int j = 0; j < 4; ++j) accS[n][j] += g4[j] * accC[n][j];
            accC[n] = vzero;
          }
        }
      }
    }
    __syncthreads();
  }

  const int row0 = wr * 16 + g16 * 4;
#pragma unroll
  for (int n = 0; n < NFW; ++n) {
    const int c = (wc * NFW + n) * 16 + (lane & 15);
    float bv = 0.f;
    if constexpr (HASBIAS) bv = bias[c];
#pragma unroll
    for (int j = 0; j < 4; ++j) {
      float v = accS[n][j] + bv;
      if constexpr (DOSILU) v = v / (1.f + __expf(-v));
      const int er = e0 + row0 + j;
      outb[(size_t)er * ob_stride + ob_off + c] = f2bf(v);
    }
  }
}

// ---------------- post-MoE per-edge ----------------
__global__ __launch_bounds__(128) void k_post1(
    const ushort* __restrict__ moeout,
    const float* __restrict__ D1g, const float* __restrict__ D2g,
    const float* __restrict__ latg, const int* __restrict__ act,
    const float* __restrict__ P0, const float* __restrict__ b0,
    const float* __restrict__ P1, const float* __restrict__ P2,
    const ushort* __restrict__ wbuf, const float* __restrict__ beg,
    const float* __restrict__ lng, const float* __restrict__ lnb,
    float* __restrict__ new_edge, ushort* __restrict__ mlp1_in) {
  __shared__ float s0[160], s1[96], s2[32], sd1[9], sd2[25], lat[128],
      wv[112], z1r[96], z2r[80], v1p[96], v2p[80], scs[64], sps[64], sg[48], pr[4];
  const int t = threadIdx.x;
  const int e = blockIdx.x;
  const int ae = act[e];
  lat[t] = latg[ae * 128 + t];
  s0[t] = bf2f(moeout[e * 288 + t]);
  if (t < 32) s0[128 + t] = bf2f(moeout[e * 288 + 128 + t]);
  if (t < 96) s1[t] = bf2f(moeout[e * 288 + 160 + t]);
  if (t < 32) s2[t] = bf2f(moeout[e * 288 + 256 + t]);
  if (t < 9)  sd1[t] = D1g[e * 9 + t];
  if (t < 25) sd2[t] = D2g[e * 25 + t];
  if (t < 112) wv[t] = bf2f(wbuf[e * 128 + t]) + beg[t];
  __syncthreads();
  if (t < 64) { float x = s0[t]; scs[t] = x / (1.f + __expf(-x)); }
  if (t < 48) sg[t] = 1.f / (1.f + __expf(-s0[64 + t]));
  if (t < 96) {
    int c = t / 3, i = t - c * 3;
    z1r[t] = sd1[i] * s1[48 + c] + sd1[3 + i] * s0[112 + c] + sd1[6 + i] * s1[c];
  }
  if (t < 80) {
    int c = t / 5, i = t - c * 5;
    z2r[t] = sd2[i] * s2[16 + c] + sd2[5 + i] * s1[80 + c] + sd2[10 + i] * s0[144 + c] +
             sd2[15 + i] * s1[32 + c] + sd2[20 + i] * s2[c];
  }
  {
    float v = lat[t];
    float sum = v, sq = v * v;
#pragma unroll
    for (int o = 32; o > 0; o >>= 1) {
      sum += __shfl_down(sum, o);
      sq += __shfl_down(sq, o);
    }
    if ((t & 63) == 0) { pr[t >> 6] = sum; pr[2 + (t >> 6)] = sq; }
  }
  __syncthreads();
  const float mu = (pr[0] + pr[1]) * (1.f / 128.f);
  const float var = (pr[2] + pr[3]) * (1.f / 128.f) - mu * mu;
  const float rs = rsqrtf(var + 1e-5f);
  if (t < 64) {
    float a = b0[t];
    for (int c = 0; c < 64; ++c) a += scs[c] * P0[c * 64 + t];
    sps[t] = a;
    mlp1_in[e * 192 + 128 + t] = f2bf(a);
  }
  if (t < 96) {
    int d = t / 3, m = t - d * 3;
    float a = 0.f;
    for (int c = 0; c < 32; ++c) a += z1r[c * 3 + m] * sg[c] * P1[c * 32 + d];
    v1p[t] = a;
  }
  if (t < 80) {
    int d = t / 5, m = t - d * 5;
    float a = 0.f;
    for (int c = 0; c < 16; ++c) a += z2r[c * 5 + m] * sg[32 + c] * P2[c * 16 + d];
    v2p[t] = a;
  }
  {
    float ln = (lat[t] - mu) * rs * lng[t] + lnb[t];
    mlp1_in[e * 192 + t] = f2bf(ln);
  }
  __syncthreads();
  for (int d = t; d < 240; d += 128) {
    float val;
    if (d < 64) val = sps[d] * wv[d];
    else if (d < 160) { int dd = d - 64; val = v1p[dd] * wv[64 + dd / 3]; }
    else { int dd = d - 160; val = v2p[dd] * wv[96 + dd / 5]; }
    new_edge[e * 240 + d] = val;
  }
}

// ---------------- final combine ----------------
__global__ __launch_bounds__(128) void k_final(
    const ushort* __restrict__ nl2, const ushort* __restrict__ tbuf,
    const float* __restrict__ cutg, const int* __restrict__ act,
    const float* __restrict__ efg, const float* __restrict__ new_edge,
    const float* __restrict__ latg,
    float* __restrict__ out_edge, float* __restrict__ out_lat) {
  __shared__ float tv[112];
  const int t = threadIdx.x;
  const int e = blockIdx.x;
  const int ae = act[e];
  if (t < 112) tv[t] = bf2f(tbuf[e * 128 + t]) * T_SCALE;
  const float cut = cutg[ae];
  out_lat[ae * 128 + t] = C_NEW * (cut * bf2f(nl2[e * 128 + t])) + C_OLD * latg[ae * 128 + t];
  __syncthreads();
  for (int d = t; d < 240; d += 128) {
    float v = C_OLD * efg[e * 240 + d] + C_NEW * new_edge[e * 240 + d];
    float f;
    if (d < 64) f = tv[d];
    else if (d < 160) f = tv[64 + (d - 64) / 3];
    else f = tv[96 + (d - 160) / 5];
    out_edge[e * 240 + d] = v * (1.f + f);
  }
}

extern "C" void kernel_launch(void* const* d_in, const int* in_sizes, int n_in,
                              void* d_out, int out_size, void* d_ws, size_t ws_size,
                              hipStream_t stream) {
  const float* latents = (const float*)d_in[0];
  const float* node_f  = (const float*)d_in[1];
  const float* edge_f  = (const float*)d_in[3];
  const float* cutoff  = (const float*)d_in[5];
  const float* eoh     = (const float*)d_in[6];
  const float* D1      = (const float*)d_in[7];
  const float* D2      = (const float*)d_in[8];
  const float* mg      = (const float*)d_in[9];
  const int*   eidx    = (const int*)d_in[10];
  const int*   act     = (const int*)d_in[11];
  const float* Wg      = (const float*)d_in[12];
  const float* W0      = (const float*)d_in[13];
  const float* W1r     = (const float*)d_in[14];
  const float* W1i     = (const float*)d_in[15];
  const float* W2r     = (const float*)d_in[16];
  const float* W2i     = (const float*)d_in[17];
  const float* P0      = (const float*)d_in[18];
  const float* b0      = (const float*)d_in[19];
  const float* P1      = (const float*)d_in[20];
  const float* P2      = (const float*)d_in[21];
  const float* We      = (const float*)d_in[22];
  const float* be      = (const float*)d_in[23];
  const float* lng     = (const float*)d_in[24];
  const float* lnb     = (const float*)d_in[25];
  const float* M1W0_   = (const float*)d_in[26];
  const float* M1b0_   = (const float*)d_in[27];
  const float* M1W1_   = (const float*)d_in[28];
  const float* M1b1_   = (const float*)d_in[29];
  const float* M1W2_   = (const float*)d_in[30];
  const float* M1b2_   = (const float*)d_in[31];
  const float* M2W0_   = (const float*)d_in[32];
  const float* M2b0_   = (const float*)d_in[33];
  const float* M2W1_   = (const float*)d_in[34];
  const float* M2b1_   = (const float*)d_in[35];
  const float* M2W2_   = (const float*)d_in[36];
  const float* M2b2_   = (const float*)d_in[37];
  const float* T0      = (const float*)d_in[38];
  const float* T1      = (const float*)d_in[39];
  const float* T2      = (const float*)d_in[40];

  float* out_edge = (float*)d_out;
  float* out_lat  = out_edge + (size_t)EDGES * 240;
  float* out_d1   = out_lat + (size_t)EDGES * 128;
  float* out_d2   = out_d1 + (size_t)EDGES * 9;

  char* ws = (char*)d_ws;
  size_t off = 0;
  auto alloc = [&](size_t bytes) -> char* {
    char* p = ws + off;
    off += (bytes + 255) & ~size_t(255);
    return p;
  };
  ushort* f_all  = (ushort*)alloc((size_t)EDGES * 720 * 2);  // region reused for MLP bufs
  float*  gfb    = (float*) alloc((size_t)EDGES * 12 * 4);
  ushort* moeout = (ushort*)alloc((size_t)EDGES * 288 * 2);
  ushort* m2in   = (ushort*)alloc((size_t)EDGES * 256 * 2);
  ushort* latbf  = (ushort*)alloc((size_t)EDGES * 128 * 2);  // reused as tbuf after We-GEMM
  ushort* wbuf   = (ushort*)alloc((size_t)EDGES * 128 * 2);
  ushort* B0t    = (ushort*)alloc(160 * 3200 * 2);
  ushort* B1t    = (ushort*)alloc(96 * 2624 * 2);
  ushort* B2t    = (ushort*)alloc(32 * 896 * 2);
  ushort* Wt1    = (ushort*)alloc(128 * 192 * 2);
  ushort* Wt2    = (ushort*)alloc(128 * 128 * 2);
  ushort* Wt3    = (ushort*)alloc(128 * 128 * 2);
  ushort* Wt4    = (ushort*)alloc(128 * 256 * 2);
  ushort* Wt5    = (ushort*)alloc(128 * 128 * 2);
  ushort* Wt6    = (ushort*)alloc(128 * 128 * 2);
  ushort* Wet    = (ushort*)alloc(128 * 128 * 2);
  ushort* Ttb    = (ushort*)alloc(128 * 128 * 2);

  // overlays inside the (dead-after-MoE) f_all region: 192+128+128+128 = 576 <= 720
  ushort* m1in = f_all;                                 // E*192
  ushort* h1   = f_all + (size_t)EDGES * 192;           // E*128
  ushort* h2   = f_all + (size_t)EDGES * 320;           // E*128
  ushort* nl2  = f_all + (size_t)EDGES * 448;           // E*128
  ushort* tbuf = latbf;

  // Always-safe output copies first.
  hipMemcpyAsync(out_lat, (const void*)latents, (size_t)EDGES * 128 * 4, hipMemcpyDeviceToDevice, stream);
  hipMemcpyAsync(out_d1, (const void*)D1, (size_t)EDGES * 9 * 4, hipMemcpyDeviceToDevice, stream);
  hipMemcpyAsync(out_d2, (const void*)D2, (size_t)EDGES * 25 * 4, hipMemcpyDeviceToDevice, stream);

  if (ws_size < off) {
    // Workspace too small: bail out cleanly (visible absmax failure, no fault).
    return;
  }

  k_pack_b0<<<2000, 256, 0, stream>>>(W0, B0t);
  k_pack_b1<<<984, 256, 0, stream>>>(W1r, W1i, B1t);
  k_pack_b2<<<112, 256, 0, stream>>>(W2r, W2i, B2t);
  k_pack_w<<<96, 256, 0, stream>>>(M1W0_, Wt1, 192, 128);
  k_pack_w<<<64, 256, 0, stream>>>(M1W1_, Wt2, 128, 128);
  k_pack_w<<<64, 256, 0, stream>>>(M1W2_, Wt3, 128, 128);
  k_pack_w<<<128, 256, 0, stream>>>(M2W0_, Wt4, 256, 128);
  k_pack_w<<<64, 256, 0, stream>>>(M2W1_, Wt5, 128, 128);
  k_pack_w<<<64, 256, 0, stream>>>(M2W2_, Wt6, 128, 128);
  k_pack_we<<<64, 256, 0, stream>>>(We, Wet);
  k_pack_tt<<<64, 256, 0, stream>>>(T0, T1, T2, Ttb);

  k_prep<<<EDGES / 4, 256, 0, stream>>>(node_f, edge_f, D1, D2, mg, Wg, latents, eoh,
                                        eidx, act, f_all, gfb, latbf, m2in);

  // MoE GEMMs (gf folded at k-group boundaries) -> bf16 moeout [0:160|160:256|256:288]
  k_gemm<3200, 11, 9, 160, 336, 0, 720, 768, false, false>
      <<<2048, 256, 0, stream>>>(f_all, B0t, gfb, nullptr, moeout, 288, 0);
  k_gemm<2624, 9, 9, 96, 288, 336, 720, 640, false, false>
      <<<2048, 256, 0, stream>>>(f_all, B1t, gfb, nullptr, moeout, 288, 160);
  k_gemm<896, 3, 9, 32, 96, 624, 720, 256, false, false>
      <<<2048, 256, 0, stream>>>(f_all, B2t, gfb, nullptr, moeout, 288, 256);

  // lat @ We (reads latbf) then eoh @ T^T (reads m2in[:,128:], writes tbuf == latbf region)
  k_gemm<128, 4, 1, 128, 128, 0, 128, 256, false, false>
      <<<2048, 256, 0, stream>>>(latbf, Wet, nullptr, nullptr, wbuf, 128, 0);
  k_gemm<128, 4, 1, 128, 128, 128, 256, 256, false, false>
      <<<2048, 256, 0, stream>>>(m2in, Ttb, nullptr, nullptr, tbuf, 128, 0);

  // new_edge staged directly in d_out edge region (k_final reads+overwrites in place)
  k_post1<<<EDGES, 128, 0, stream>>>(moeout, D1, D2, latents, act,
                                     P0, b0, P1, P2, wbuf, be, lng, lnb, out_edge, m1in);

  // MLP1: 192->128 silu, 128->128 silu, 128->128 (into m2in[:,0:128])
  k_gemm<192, 6, 1, 128, 192, 0, 192, 384, true, true>
      <<<2048, 256, 0, stream>>>(m1in, Wt1, nullptr, M1b0_, h1, 128, 0);
  k_gemm<128, 4, 1, 128, 128, 0, 128, 256, true, true>
      <<<2048, 256, 0, stream>>>(h1, Wt2, nullptr, M1b1_, h2, 128, 0);
  k_gemm<128, 4, 1, 128, 128, 0, 128, 256, true, false>
      <<<2048, 256, 0, stream>>>(h2, Wt3, nullptr, M1b2_, m2in, 256, 0);
  // MLP2: 256->128 silu, 128->128 silu, 128->128 -> nl2 (bf16)
  k_gemm<256, 8, 1, 128, 256, 0, 256, 512, true, true>
      <<<2048, 256, 0, stream>>>(m2in, Wt4, nullptr, M2b0_, h1, 128, 0);
  k_gemm<128, 4, 1, 128, 128, 0, 128, 256, true, true>
      <<<2048, 256, 0, stream>>>(h1, Wt5, nullptr, M2b1_, h2, 128, 0);
  k_gemm<128, 4, 1, 128, 128, 0, 128, 256, true, false>
      <<<2048, 256, 0, stream>>>(h2, Wt6, nullptr, M2b2_, nl2, 128, 0);

  k_final<<<EDGES, 128, 0, stream>>>(nl2, tbuf, cutoff, act, edge_f, out_edge, latents,
                                     out_edge, out_lat);
}

// Round 3
// 723.413 us; speedup vs baseline: 1.2880x; 1.2880x over previous
//
#include <hip/hip_runtime.h>
#include <hip/hip_bf16.h>
#include <stdint.h>

#define EDGES 65536

typedef unsigned int uint;
typedef unsigned short ushort;
using bf16x8 = __attribute__((ext_vector_type(8))) __bf16;
using f32x4  = __attribute__((ext_vector_type(4))) float;
using uintx4 = __attribute__((ext_vector_type(4))) uint;
using float4v = __attribute__((ext_vector_type(4))) float;

#define C_OLD 0.8944271909999159f
#define C_NEW 0.4472135954999579f
#define T_SCALE 0.08838834764831845f

__device__ __forceinline__ ushort f2bf(float f) {
  uint x = __builtin_bit_cast(uint, f);
  uint r = x + 0x7FFFu + ((x >> 16) & 1u);
  return (ushort)(r >> 16);
}
__device__ __forceinline__ float bf2f(ushort u) {
  uint x = (uint)u << 16;
  return __builtin_bit_cast(float, x);
}

// ---------------- weight pack kernels ----------------
__global__ __launch_bounds__(256) void k_pack_b0(const float* __restrict__ W0, ushort* __restrict__ B) {
  int idx = blockIdx.x * 256 + threadIdx.x;
  if (idx >= 160 * 3200) return;
  int o = idx / 3200, kf = idx - o * 3200;
  int k = kf / 352, f = kf - k * 352;
  float v = (k < 9 && f < 336) ? W0[k * 53760 + f * 160 + o] : 0.f;
  B[idx] = f2bf(v);
}
__global__ __launch_bounds__(256) void k_pack_b1(const float* __restrict__ Wr, const float* __restrict__ Wi, ushort* __restrict__ B) {
  int idx = blockIdx.x * 256 + threadIdx.x;
  if (idx >= 96 * 2624) return;
  int c = idx / 2624, kf = idx - c * 2624;
  int k = kf / 288, f = kf - k * 288;
  float v = 0.f;
  if (k < 9) {
    if (c < 48) v = (f < 144) ? Wr[k * 6912 + f * 48 + c] : -Wi[k * 6912 + (f - 144) * 48 + c];
    else        v = (f < 144) ? Wi[k * 6912 + f * 48 + (c - 48)] : Wr[k * 6912 + (f - 144) * 48 + (c - 48)];
  }
  B[idx] = f2bf(v);
}
__global__ __launch_bounds__(256) void k_pack_b2(const float* __restrict__ Wr, const float* __restrict__ Wi, ushort* __restrict__ B) {
  int idx = blockIdx.x * 256 + threadIdx.x;
  if (idx >= 32 * 896) return;
  int c = idx / 896, kf = idx - c * 896;
  int k = kf / 96, f = kf - k * 96;
  float v = 0.f;
  if (k < 9) {
    if (c < 16) v = (f < 48) ? Wr[k * 768 + f * 16 + c] : -Wi[k * 768 + (f - 48) * 16 + c];
    else        v = (f < 48) ? Wi[k * 768 + f * 16 + (c - 16)] : Wr[k * 768 + (f - 48) * 16 + (c - 16)];
  }
  B[idx] = f2bf(v);
}
// all small weight packs in one launch (8 matrices)
struct PackPtrs {
  const float *s0, *s1, *s2, *s3, *s4, *s5, *we, *t0, *t1, *t2;
  ushort *d0, *d1, *d2, *d3, *d4, *d5, *dwe, *dtt;
};
__global__ __launch_bounds__(256) void k_pack_small(PackPtrs p) {
  int idx = blockIdx.x * 256 + threadIdx.x;
  if (idx < 24576) {  // M1W0: K=192
    int n = idx / 192, k = idx - n * 192;
    p.d0[idx] = f2bf(p.s0[k * 128 + n]);
  } else if (idx < 40960) {
    int q = idx - 24576; int n = q >> 7, k = q & 127;
    p.d1[q] = f2bf(p.s1[k * 128 + n]);
  } else if (idx < 57344) {
    int q = idx - 40960; int n = q >> 7, k = q & 127;
    p.d2[q] = f2bf(p.s2[k * 128 + n]);
  } else if (idx < 90112) {  // M2W0: K=256
    int q = idx - 57344; int n = q / 256, k = q - n * 256;
    p.d3[q] = f2bf(p.s3[k * 128 + n]);
  } else if (idx < 106496) {
    int q = idx - 90112; int n = q >> 7, k = q & 127;
    p.d4[q] = f2bf(p.s4[k * 128 + n]);
  } else if (idx < 122880) {
    int q = idx - 106496; int n = q >> 7, k = q & 127;
    p.d5[q] = f2bf(p.s5[k * 128 + n]);
  } else if (idx < 139264) {  // We: (128,112) -> (128n,128k) pad
    int q = idx - 122880; int n = q >> 7, k = q & 127;
    p.dwe[q] = f2bf((n < 112) ? p.we[k * 112 + n] : 0.f);
  } else if (idx < 155648) {  // Ttb
    int q = idx - 139264; int o = q >> 7, h = q & 127;
    float v = 0.f;
    if (o < 64) v = p.t0[o * 128 + h];
    else if (o < 96) v = p.t1[(o - 64) * 128 + h];
    else if (o < 112) v = p.t2[(o - 96) * 128 + h];
    p.dtt[q] = f2bf(v);
  }
}

// ---------------- prep: gather + Wigner rotate + softmax gates (wave-per-edge) ----------------
__global__ __launch_bounds__(256) void k_prep(
    const float* __restrict__ node_f, const float* __restrict__ edge_f,
    const float* __restrict__ D1g, const float* __restrict__ D2g,
    const float* __restrict__ mg_g, const float* __restrict__ Wg,
    const float* __restrict__ latg, const float* __restrict__ eohg,
    const int* __restrict__ eidx, const int* __restrict__ act,
    ushort* __restrict__ f_all, float* __restrict__ gf_out,
    ushort* __restrict__ lat_bf, ushort* __restrict__ mlp2_in) {
  // per-warp float region: nc240 ef240 nn240 d1:9 d2:25 mg:64 lg:8 pad:2 row:720 ushort(=360 f)
  __shared__ float sh[4][1188];
  const int w = threadIdx.x >> 6, lane = threadIdx.x & 63;
  const int e = blockIdx.x * 4 + w;
  float* s = sh[w];
  float* s_nc = s;
  float* s_ef = s + 240;
  float* s_nn = s + 480;
  float* s_d1 = s + 720;
  float* s_d2 = s + 729;
  float* s_mg = s + 754;
  float* s_lg = s + 818;
  ushort* row = (ushort*)(s + 828);  // 720 ushorts, 16B-aligned (828*4 % 16 == 0)
  const int ae = act[e];
  const int ec = eidx[ae], en = eidx[EDGES + ae];
  // vector loads: 240 floats = 60 float4 per stream
  if (lane < 60) {
    ((float4v*)s_nc)[lane] = ((const float4v*)(node_f + (size_t)ec * 240))[lane];
    ((float4v*)s_ef)[lane] = ((const float4v*)(edge_f + (size_t)e * 240))[lane];
    ((float4v*)s_nn)[lane] = ((const float4v*)(node_f + (size_t)en * 240))[lane];
  }
  if (lane < 9)  s_d1[lane] = D1g[e * 9 + lane];
  if (lane < 25) s_d2[lane] = D2g[e * 25 + lane];
  s_mg[lane] = mg_g[e * 64 + lane];
  // lat -> bf16 (packed pairs), eoh -> bf16 into m2in upper half
  {
    const float* lp = latg + (size_t)ae * 128;
    float a0 = lp[2 * lane], a1 = lp[2 * lane + 1];
    ((uint*)lat_bf)[(size_t)e * 64 + lane] = (uint)f2bf(a0) | ((uint)f2bf(a1) << 16);
    const float* ep = eohg + (size_t)e * 128;
    a0 = ep[2 * lane]; a1 = ep[2 * lane + 1];
    ((uint*)mlp2_in)[(size_t)e * 128 + 64 + lane] = (uint)f2bf(a0) | ((uint)f2bf(a1) << 16);
  }
  // gate logits (wave-private LDS; same-wave ordering via lgkmcnt)
  if (lane < 8) {
    float a = 0.f;
    for (int h = 0; h < 64; ++h) a += s_mg[h] * Wg[h * 8 + lane];
    s_lg[lane] = a;
  }
  if (lane < 12) {
    float m = s_lg[0];
    for (int j = 1; j < 8; ++j) m = fmaxf(m, s_lg[j]);
    float den = 0.f;
    for (int j = 0; j < 8; ++j) den += __expf(s_lg[j] - m);
    float v = 0.f;
    if (lane < 8) v = __expf(s_lg[lane] - m) / den;
    else if (lane == 8) v = 1.f;
    gf_out[e * 12 + lane] = v;
  }
  // scalars: row[0:64]=nc, [64:128]=ef, [128:192]=nn
  row[lane]       = f2bf(s_nc[lane]);
  row[64 + lane]  = f2bf(s_ef[lane]);
  row[128 + lane] = f2bf(s_nn[lane]);
  // y1: 288 vals (i in 0..2, c in 0..95) -> segments {480,192,336}+c
#pragma unroll
  for (int it = 0; it < 5; ++it) {
    int q = lane + it * 64;
    if (q < 288) {
      int i = q / 96, c = q - i * 96;
      const float* src = (c < 32) ? s_nc : (c < 64) ? s_ef : s_nn;
      int base = 64 + (c & 31) * 3;
      float v = s_d1[i * 3] * src[base] + s_d1[i * 3 + 1] * src[base + 1] + s_d1[i * 3 + 2] * src[base + 2];
      int dst = (i == 0) ? 480 : (i == 1) ? 192 : 336;
      row[dst + c] = f2bf(v);
    }
  }
  // y2: 240 vals (i in 0..4, c in 0..47) -> segments {672,576,288,432,624}+c
#pragma unroll
  for (int it = 0; it < 4; ++it) {
    int q = lane + it * 64;
    if (q < 240) {
      int i = q / 48, c = q - i * 48;
      const float* src = (c < 16) ? s_nc : (c < 32) ? s_ef : s_nn;
      int base = 160 + (c & 15) * 5;
      float v = s_d2[i * 5] * src[base] + s_d2[i * 5 + 1] * src[base + 1] +
                s_d2[i * 5 + 2] * src[base + 2] + s_d2[i * 5 + 3] * src[base + 3] +
                s_d2[i * 5 + 4] * src[base + 4];
      int dst = (i == 0) ? 672 : (i == 1) ? 576 : (i == 2) ? 288 : (i == 3) ? 432 : 624;
      row[dst + c] = f2bf(v);
    }
  }
  // write out 720 ushorts = 90 x 16B
  const uintx4* row4 = (const uintx4*)row;
  uintx4* dst4 = (uintx4*)(f_all + (size_t)e * 720);
#pragma unroll
  for (int it = 0; it < 2; ++it) {
    int q = lane + it * 64;
    if (q < 90) dst4[q] = row4[q];
  }
}

// ---------------- generic bf16 MFMA GEMM, optional 9-expert gf-fold, bf16 out ----------------
template <int KZP, int SPG, int NGRP, int NCOL, int FPREAL, int FOFF, int ASTRIDE, int ROWB,
          bool HASBIAS, bool DOSILU>
__global__ __launch_bounds__(256) void k_gemm(
    const ushort* __restrict__ A, const ushort* __restrict__ Bt,
    const float* __restrict__ gf, const float* __restrict__ bias,
    ushort* __restrict__ outb, int ob_stride, int ob_off) {
  constexpr int NF = NCOL / 16;
  constexpr int NFW = NF / 2;
  constexpr int CPR = ROWB / 16;
  constexpr int SMEM = 32 * ROWB + NCOL * 128 + ((NGRP > 1) ? 1536 : 16);
  static_assert(ROWB % 128 == 0 && NF % 2 == 0 && KZP % 64 == 0 && (CPR % 8) == 0, "geom");
  __shared__ uintx4 smem4[SMEM / 16];
  char* sm = (char*)smem4;
  char* f_lds = sm;
  char* b_lds = sm + 32 * ROWB;
  float* gf_lds = (float*)(sm + 32 * ROWB + NCOL * 128);
  const int tid = threadIdx.x;
  const int lane = tid & 63, w = tid >> 6;
  const int wr = w >> 1, wc = w & 1;
  const int e0 = blockIdx.x * 32;
  const f32x4 vzero = {0.f, 0.f, 0.f, 0.f};

#pragma unroll
  for (int it = 0; it < CPR / 8; ++it) {
    int q = tid + it * 256;
    int r = q / CPR, ch = q - r * CPR;
    uintx4 v = {0u, 0u, 0u, 0u};
    if (ch * 8 < FPREAL)
      v = *(const uintx4*)(A + (size_t)(e0 + r) * ASTRIDE + FOFF + ch * 8);
    *(uintx4*)(f_lds + r * ROWB + ((ch * 16) ^ ((r & 7) << 4))) = v;
  }
  if constexpr (NGRP > 1) {
    for (int q = tid; q < 384; q += 256)
      gf_lds[q] = gf[(e0 + q / 12) * 12 + (q - (q / 12) * 12)];
  }
  __syncthreads();

  f32x4 accS[NFW];
#pragma unroll
  for (int n = 0; n < NFW; ++n) accS[n] = vzero;
  f32x4 accC[(NGRP > 1) ? NFW : 1];
  if constexpr (NGRP > 1) {
#pragma unroll
    for (int n = 0; n < NFW; ++n) accC[n] = vzero;
  }
  const int g16 = lane >> 4;
  const int rA = wr * 16 + (lane & 15);
  const int abase = rA * ROWB;
  const int axor = (rA & 7) << 4;

  constexpr int NT2 = KZP / 64;
  for (int t2 = 0; t2 < NT2; ++t2) {
#pragma unroll
    for (int it = 0; it < NCOL / 32; ++it) {
      int q = tid + it * 256;
      int c = q >> 3, ch = q & 7;
      uintx4 v = *(const uintx4*)(Bt + (size_t)c * KZP + t2 * 64 + ch * 8);
      *(uintx4*)(b_lds + c * 128 + ((ch ^ (c & 7)) << 4)) = v;
    }
    __syncthreads();
#pragma unroll
    for (int s = 0; s < 2; ++s) {
      const int t = t2 * 2 + s;
      const int g = t / SPG;
      const int ts = t - g * SPG;
      const int fidx = ts * 32 + g16 * 8;
      bf16x8 a = *(const bf16x8*)(f_lds + abase + ((fidx * 2) ^ axor));
#pragma unroll
      for (int n = 0; n < NFW; ++n) {
        const int cB = (wc * NFW + n) * 16 + (lane & 15);
        const int ch = s * 4 + g16;
        bf16x8 b = *(const bf16x8*)(b_lds + cB * 128 + ((ch ^ (cB & 7)) << 4));
        if constexpr (NGRP > 1)
          accC[n] = __builtin_amdgcn_mfma_f32_16x16x32_bf16(a, b, accC[n], 0, 0, 0);
        else
          accS[n] = __builtin_amdgcn_mfma_f32_16x16x32_bf16(a, b, accS[n], 0, 0, 0);
      }
      if constexpr (NGRP > 1) {
        if (ts == SPG - 1 && g < NGRP) {
          float g4[4];
#pragma unroll
          for (int j = 0; j < 4; ++j)
            g4[j] = gf_lds[(wr * 16 + g16 * 4 + j) * 12 + g];
#pragma unroll
          for (int n = 0; n < NFW; ++n) {
#pragma unroll
            for (int j = 0; j < 4; ++j) accS[n][j] += g4[j] * accC[n][j];
            accC[n] = vzero;
          }
        }
      }
    }
    __syncthreads();
  }

  const int row0 = wr * 16 + g16 * 4;
#pragma unroll
  for (int n = 0; n < NFW; ++n) {
    const int c = (wc * NFW + n) * 16 + (lane & 15);
    float bv = 0.f;
    if constexpr (HASBIAS) bv = bias[c];
#pragma unroll
    for (int j = 0; j < 4; ++j) {
      float v = accS[n][j] + bv;
      if constexpr (DOSILU) v = v / (1.f + __expf(-v));
      const int er = e0 + row0 + j;
      outb[(size_t)er * ob_stride + ob_off + c] = f2bf(v);
    }
  }
}

// ---------------- post-MoE per-edge ----------------
__global__ __launch_bounds__(128) void k_post1(
    const ushort* __restrict__ moeout,
    const float* __restrict__ D1g, const float* __restrict__ D2g,
    const float* __restrict__ latg, const int* __restrict__ act,
    const float* __restrict__ P0, const float* __restrict__ b0,
    const float* __restrict__ P1, const float* __restrict__ P2,
    const ushort* __restrict__ wbuf, const float* __restrict__ beg,
    const float* __restrict__ lng, const float* __restrict__ lnb,
    float* __restrict__ new_edge, ushort* __restrict__ mlp1_in) {
  __shared__ float s0[160], s1[96], s2[32], sd1[9], sd2[25], lat[128],
      wv[112], z1r[96], z2r[80], v1p[96], v2p[80], scs[64], sps[64], sg[48], pr[4];
  const int t = threadIdx.x;
  const int e = blockIdx.x;
  const int ae = act[e];
  lat[t] = latg[ae * 128 + t];
  s0[t] = bf2f(moeout[e * 288 + t]);
  if (t < 32) s0[128 + t] = bf2f(moeout[e * 288 + 128 + t]);
  if (t < 96) s1[t] = bf2f(moeout[e * 288 + 160 + t]);
  if (t < 32) s2[t] = bf2f(moeout[e * 288 + 256 + t]);
  if (t < 9)  sd1[t] = D1g[e * 9 + t];
  if (t < 25) sd2[t] = D2g[e * 25 + t];
  if (t < 112) wv[t] = bf2f(wbuf[e * 128 + t]) + beg[t];
  __syncthreads();
  if (t < 64) { float x = s0[t]; scs[t] = x / (1.f + __expf(-x)); }
  if (t < 48) sg[t] = 1.f / (1.f + __expf(-s0[64 + t]));
  if (t < 96) {
    int c = t / 3, i = t - c * 3;
    z1r[t] = sd1[i] * s1[48 + c] + sd1[3 + i] * s0[112 + c] + sd1[6 + i] * s1[c];
  }
  if (t < 80) {
    int c = t / 5, i = t - c * 5;
    z2r[t] = sd2[i] * s2[16 + c] + sd2[5 + i] * s1[80 + c] + sd2[10 + i] * s0[144 + c] +
             sd2[15 + i] * s1[32 + c] + sd2[20 + i] * s2[c];
  }
  {
    float v = lat[t];
    float sum = v, sq = v * v;
#pragma unroll
    for (int o = 32; o > 0; o >>= 1) {
      sum += __shfl_down(sum, o);
      sq += __shfl_down(sq, o);
    }
    if ((t & 63) == 0) { pr[t >> 6] = sum; pr[2 + (t >> 6)] = sq; }
  }
  __syncthreads();
  const float mu = (pr[0] + pr[1]) * (1.f / 128.f);
  const float var = (pr[2] + pr[3]) * (1.f / 128.f) - mu * mu;
  const float rs = rsqrtf(var + 1e-5f);
  if (t < 64) {
    float a = b0[t];
    for (int c = 0; c < 64; ++c) a += scs[c] * P0[c * 64 + t];
    sps[t] = a;
    mlp1_in[e * 192 + 128 + t] = f2bf(a);
  }
  if (t < 96) {
    int d = t / 3, m = t - d * 3;
    float a = 0.f;
    for (int c = 0; c < 32; ++c) a += z1r[c * 3 + m] * sg[c] * P1[c * 32 + d];
    v1p[t] = a;
  }
  if (t < 80) {
    int d = t / 5, m = t - d * 5;
    float a = 0.f;
    for (int c = 0; c < 16; ++c) a += z2r[c * 5 + m] * sg[32 + c] * P2[c * 16 + d];
    v2p[t] = a;
  }
  {
    float ln = (lat[t] - mu) * rs * lng[t] + lnb[t];
    mlp1_in[e * 192 + t] = f2bf(ln);
  }
  __syncthreads();
  for (int d = t; d < 240; d += 128) {
    float val;
    if (d < 64) val = sps[d] * wv[d];
    else if (d < 160) { int dd = d - 64; val = v1p[dd] * wv[64 + dd / 3]; }
    else { int dd = d - 160; val = v2p[dd] * wv[96 + dd / 5]; }
    new_edge[e * 240 + d] = val;
  }
}

// ---------------- final combine ----------------
__global__ __launch_bounds__(128) void k_final(
    const ushort* __restrict__ nl2, const ushort* __restrict__ tbuf,
    const float* __restrict__ cutg, const int* __restrict__ act,
    const float* __restrict__ efg, const float* __restrict__ new_edge,
    const float* __restrict__ latg,
    float* __restrict__ out_edge, float* __restrict__ out_lat) {
  __shared__ float tv[112];
  const int t = threadIdx.x;
  const int e = blockIdx.x;
  const int ae = act[e];
  if (t < 112) tv[t] = bf2f(tbuf[e * 128 + t]) * T_SCALE;
  const float cut = cutg[ae];
  out_lat[ae * 128 + t] = C_NEW * (cut * bf2f(nl2[e * 128 + t])) + C_OLD * latg[ae * 128 + t];
  __syncthreads();
  for (int d = t; d < 240; d += 128) {
    float v = C_OLD * efg[e * 240 + d] + C_NEW * new_edge[e * 240 + d];
    float f;
    if (d < 64) f = tv[d];
    else if (d < 160) f = tv[64 + (d - 64) / 3];
    else f = tv[96 + (d - 160) / 5];
    out_edge[e * 240 + d] = v * (1.f + f);
  }
}

extern "C" void kernel_launch(void* const* d_in, const int* in_sizes, int n_in,
                              void* d_out, int out_size, void* d_ws, size_t ws_size,
                              hipStream_t stream) {
  const float* latents = (const float*)d_in[0];
  const float* node_f  = (const float*)d_in[1];
  const float* edge_f  = (const float*)d_in[3];
  const float* cutoff  = (const float*)d_in[5];
  const float* eoh     = (const float*)d_in[6];
  const float* D1      = (const float*)d_in[7];
  const float* D2      = (const float*)d_in[8];
  const float* mg      = (const float*)d_in[9];
  const int*   eidx    = (const int*)d_in[10];
  const int*   act     = (const int*)d_in[11];
  const float* Wg      = (const float*)d_in[12];
  const float* W0      = (const float*)d_in[13];
  const float* W1r     = (const float*)d_in[14];
  const float* W1i     = (const float*)d_in[15];
  const float* W2r     = (const float*)d_in[16];
  const float* W2i     = (const float*)d_in[17];
  const float* P0      = (const float*)d_in[18];
  const float* b0      = (const float*)d_in[19];
  const float* P1      = (const float*)d_in[20];
  const float* P2      = (const float*)d_in[21];
  const float* We      = (const float*)d_in[22];
  const float* be      = (const float*)d_in[23];
  const float* lng     = (const float*)d_in[24];
  const float* lnb     = (const float*)d_in[25];
  const float* M1W0_   = (const float*)d_in[26];
  const float* M1b0_   = (const float*)d_in[27];
  const float* M1W1_   = (const float*)d_in[28];
  const float* M1b1_   = (const float*)d_in[29];
  const float* M1W2_   = (const float*)d_in[30];
  const float* M1b2_   = (const float*)d_in[31];
  const float* M2W0_   = (const float*)d_in[32];
  const float* M2b0_   = (const float*)d_in[33];
  const float* M2W1_   = (const float*)d_in[34];
  const float* M2b1_   = (const float*)d_in[35];
  const float* M2W2_   = (const float*)d_in[36];
  const float* M2b2_   = (const float*)d_in[37];
  const float* T0      = (const float*)d_in[38];
  const float* T1      = (const float*)d_in[39];
  const float* T2      = (const float*)d_in[40];

  float* out_edge = (float*)d_out;
  float* out_lat  = out_edge + (size_t)EDGES * 240;
  float* out_d1   = out_lat + (size_t)EDGES * 128;
  float* out_d2   = out_d1 + (size_t)EDGES * 9;

  char* ws = (char*)d_ws;
  size_t off = 0;
  auto alloc = [&](size_t bytes) -> char* {
    char* p = ws + off;
    off += (bytes + 255) & ~size_t(255);
    return p;
  };
  ushort* f_all  = (ushort*)alloc((size_t)EDGES * 720 * 2);  // region reused for MLP bufs
  float*  gfb    = (float*) alloc((size_t)EDGES * 12 * 4);
  ushort* moeout = (ushort*)alloc((size_t)EDGES * 288 * 2);
  ushort* m2in   = (ushort*)alloc((size_t)EDGES * 256 * 2);
  ushort* latbf  = (ushort*)alloc((size_t)EDGES * 128 * 2);  // reused as tbuf after We-GEMM
  ushort* wbuf   = (ushort*)alloc((size_t)EDGES * 128 * 2);
  ushort* B0t    = (ushort*)alloc(160 * 3200 * 2);
  ushort* B1t    = (ushort*)alloc(96 * 2624 * 2);
  ushort* B2t    = (ushort*)alloc(32 * 896 * 2);
  ushort* Wt1    = (ushort*)alloc(128 * 192 * 2);
  ushort* Wt2    = (ushort*)alloc(128 * 128 * 2);
  ushort* Wt3    = (ushort*)alloc(128 * 128 * 2);
  ushort* Wt4    = (ushort*)alloc(128 * 256 * 2);
  ushort* Wt5    = (ushort*)alloc(128 * 128 * 2);
  ushort* Wt6    = (ushort*)alloc(128 * 128 * 2);
  ushort* Wet    = (ushort*)alloc(128 * 128 * 2);
  ushort* Ttb    = (ushort*)alloc(128 * 128 * 2);

  // overlays inside the (dead-after-MoE) f_all region: 192+128+128+128 = 576 <= 720
  ushort* m1in = f_all;                                 // E*192
  ushort* h1   = f_all + (size_t)EDGES * 192;           // E*128
  ushort* h2   = f_all + (size_t)EDGES * 320;           // E*128
  ushort* nl2  = f_all + (size_t)EDGES * 448;           // E*128
  ushort* tbuf = latbf;

  // Output copies (lat copy required: reference keeps old latents for non-active edges).
  hipMemcpyAsync(out_lat, (const void*)latents, (size_t)EDGES * 128 * 4, hipMemcpyDeviceToDevice, stream);
  hipMemcpyAsync(out_d1, (const void*)D1, (size_t)EDGES * 9 * 4, hipMemcpyDeviceToDevice, stream);
  hipMemcpyAsync(out_d2, (const void*)D2, (size_t)EDGES * 25 * 4, hipMemcpyDeviceToDevice, stream);

  if (ws_size < off) return;  // visible absmax failure instead of fault

  k_pack_b0<<<2000, 256, 0, stream>>>(W0, B0t);
  k_pack_b1<<<984, 256, 0, stream>>>(W1r, W1i, B1t);
  k_pack_b2<<<112, 256, 0, stream>>>(W2r, W2i, B2t);
  PackPtrs pp = {M1W0_, M1W1_, M1W2_, M2W0_, M2W1_, M2W2_, We, T0, T1, T2,
                 Wt1, Wt2, Wt3, Wt4, Wt5, Wt6, Wet, Ttb};
  k_pack_small<<<608, 256, 0, stream>>>(pp);

  k_prep<<<EDGES / 4, 256, 0, stream>>>(node_f, edge_f, D1, D2, mg, Wg, latents, eoh,
                                        eidx, act, f_all, gfb, latbf, m2in);

  // MoE GEMMs (gf folded at k-group boundaries) -> bf16 moeout [0:160|160:256|256:288]
  k_gemm<3200, 11, 9, 160, 336, 0, 720, 768, false, false>
      <<<2048, 256, 0, stream>>>(f_all, B0t, gfb, nullptr, moeout, 288, 0);
  k_gemm<2624, 9, 9, 96, 288, 336, 720, 640, false, false>
      <<<2048, 256, 0, stream>>>(f_all, B1t, gfb, nullptr, moeout, 288, 160);
  k_gemm<896, 3, 9, 32, 96, 624, 720, 256, false, false>
      <<<2048, 256, 0, stream>>>(f_all, B2t, gfb, nullptr, moeout, 288, 256);

  // lat @ We (reads latbf) then eoh @ T^T (reads m2in[:,128:], writes tbuf == latbf region)
  k_gemm<128, 4, 1, 128, 128, 0, 128, 256, false, false>
      <<<2048, 256, 0, stream>>>(latbf, Wet, nullptr, nullptr, wbuf, 128, 0);
  k_gemm<128, 4, 1, 128, 128, 128, 256, 256, false, false>
      <<<2048, 256, 0, stream>>>(m2in, Ttb, nullptr, nullptr, tbuf, 128, 0);

  // new_edge staged directly in d_out edge region (k_final reads+overwrites in place)
  k_post1<<<EDGES, 128, 0, stream>>>(moeout, D1, D2, latents, act,
                                     P0, b0, P1, P2, wbuf, be, lng, lnb, out_edge, m1in);

  // MLP1: 192->128 silu, 128->128 silu, 128->128 (into m2in[:,0:128])
  k_gemm<192, 6, 1, 128, 192, 0, 192, 384, true, true>
      <<<2048, 256, 0, stream>>>(m1in, Wt1, nullptr, M1b0_, h1, 128, 0);
  k_gemm<128, 4, 1, 128, 128, 0, 128, 256, true, true>
      <<<2048, 256, 0, stream>>>(h1, Wt2, nullptr, M1b1_, h2, 128, 0);
  k_gemm<128, 4, 1, 128, 128, 0, 128, 256, true, false>
      <<<2048, 256, 0, stream>>>(h2, Wt3, nullptr, M1b2_, m2in, 256, 0);
  // MLP2: 256->128 silu, 128->128 silu, 128->128 -> nl2 (bf16)
  k_gemm<256, 8, 1, 128, 256, 0, 256, 512, true, true>
      <<<2048, 256, 0, stream>>>(m2in, Wt4, nullptr, M2b0_, h1, 128, 0);
  k_gemm<128, 4, 1, 128, 128, 0, 128, 256, true, true>
      <<<2048, 256, 0, stream>>>(h1, Wt5, nullptr, M2b1_, h2, 128, 0);
  k_gemm<128, 4, 1, 128, 128, 0, 128, 256, true, false>
      <<<2048, 256, 0, stream>>>(h2, Wt6, nullptr, M2b2_, nl2, 128, 0);

  k_final<<<EDGES, 128, 0, stream>>>(nl2, tbuf, cutoff, act, edge_f, out_edge, latents,
                                     out_edge, out_lat);
}

// Round 4
// 652.300 us; speedup vs baseline: 1.4284x; 1.1090x over previous
//
#include <hip/hip_runtime.h>
#include <hip/hip_bf16.h>
#include <stdint.h>

#define EDGES 65536

typedef unsigned int uint;
typedef unsigned short ushort;
using bf16x8 = __attribute__((ext_vector_type(8))) __bf16;
using f32x4  = __attribute__((ext_vector_type(4))) float;
using uintx4 = __attribute__((ext_vector_type(4))) uint;
using float4v = __attribute__((ext_vector_type(4))) float;

#define C_OLD 0.8944271909999159f
#define C_NEW 0.4472135954999579f
#define T_SCALE 0.08838834764831845f

__device__ __forceinline__ ushort f2bf(float f) {
  uint x = __builtin_bit_cast(uint, f);
  uint r = x + 0x7FFFu + ((x >> 16) & 1u);
  return (ushort)(r >> 16);
}
__device__ __forceinline__ float bf2f(ushort u) {
  uint x = (uint)u << 16;
  return __builtin_bit_cast(float, x);
}
__device__ __forceinline__ void gload16(const void* g, void* l) {
  __builtin_amdgcn_global_load_lds(
      (const __attribute__((address_space(1))) void*)g,
      (__attribute__((address_space(3))) void*)l, 16, 0, 0);
}

// ---------------- weight pack kernels ----------------
__global__ __launch_bounds__(256) void k_pack_b0(const float* __restrict__ W0, ushort* __restrict__ B) {
  int idx = blockIdx.x * 256 + threadIdx.x;
  if (idx >= 160 * 3200) return;
  int o = idx / 3200, kf = idx - o * 3200;
  int k = kf / 352, f = kf - k * 352;
  float v = (k < 9 && f < 336) ? W0[k * 53760 + f * 160 + o] : 0.f;
  B[idx] = f2bf(v);
}
__global__ __launch_bounds__(256) void k_pack_b1(const float* __restrict__ Wr, const float* __restrict__ Wi, ushort* __restrict__ B) {
  int idx = blockIdx.x * 256 + threadIdx.x;
  if (idx >= 96 * 2624) return;
  int c = idx / 2624, kf = idx - c * 2624;
  int k = kf / 288, f = kf - k * 288;
  float v = 0.f;
  if (k < 9) {
    if (c < 48) v = (f < 144) ? Wr[k * 6912 + f * 48 + c] : -Wi[k * 6912 + (f - 144) * 48 + c];
    else        v = (f < 144) ? Wi[k * 6912 + f * 48 + (c - 48)] : Wr[k * 6912 + (f - 144) * 48 + (c - 48)];
  }
  B[idx] = f2bf(v);
}
__global__ __launch_bounds__(256) void k_pack_b2(const float* __restrict__ Wr, const float* __restrict__ Wi, ushort* __restrict__ B) {
  int idx = blockIdx.x * 256 + threadIdx.x;
  if (idx >= 32 * 896) return;
  int c = idx / 896, kf = idx - c * 896;
  int k = kf / 96, f = kf - k * 96;
  float v = 0.f;
  if (k < 9) {
    if (c < 16) v = (f < 48) ? Wr[k * 768 + f * 16 + c] : -Wi[k * 768 + (f - 48) * 16 + c];
    else        v = (f < 48) ? Wi[k * 768 + f * 16 + (c - 16)] : Wr[k * 768 + (f - 48) * 16 + (c - 16)];
  }
  B[idx] = f2bf(v);
}
struct PackPtrs {
  const float *s0, *s1, *s2, *s3, *s4, *s5, *we, *t0, *t1, *t2;
  ushort *d0, *d1, *d2, *d3, *d4, *d5, *dwe, *dtt;
};
__global__ __launch_bounds__(256) void k_pack_small(PackPtrs p) {
  int idx = blockIdx.x * 256 + threadIdx.x;
  if (idx < 24576) {
    int n = idx / 192, k = idx - n * 192;
    p.d0[idx] = f2bf(p.s0[k * 128 + n]);
  } else if (idx < 40960) {
    int q = idx - 24576; int n = q >> 7, k = q & 127;
    p.d1[q] = f2bf(p.s1[k * 128 + n]);
  } else if (idx < 57344) {
    int q = idx - 40960; int n = q >> 7, k = q & 127;
    p.d2[q] = f2bf(p.s2[k * 128 + n]);
  } else if (idx < 90112) {
    int q = idx - 57344; int n = q / 256, k = q - n * 256;
    p.d3[q] = f2bf(p.s3[k * 128 + n]);
  } else if (idx < 106496) {
    int q = idx - 90112; int n = q >> 7, k = q & 127;
    p.d4[q] = f2bf(p.s4[k * 128 + n]);
  } else if (idx < 122880) {
    int q = idx - 106496; int n = q >> 7, k = q & 127;
    p.d5[q] = f2bf(p.s5[k * 128 + n]);
  } else if (idx < 139264) {
    int q = idx - 122880; int n = q >> 7, k = q & 127;
    p.dwe[q] = f2bf((n < 112) ? p.we[k * 112 + n] : 0.f);
  } else if (idx < 155648) {
    int q = idx - 139264; int o = q >> 7, h = q & 127;
    float v = 0.f;
    if (o < 64) v = p.t0[o * 128 + h];
    else if (o < 96) v = p.t1[(o - 64) * 128 + h];
    else if (o < 112) v = p.t2[(o - 96) * 128 + h];
    p.dtt[q] = f2bf(v);
  }
}

// ---------------- prep: gather + Wigner rotate + softmax gates (wave-per-edge) ----------------
// f_all row (736 ushorts): [x0 192 | y1_i1 96 | y2_i2 48 | zeros 16 | y1_i2 96 | y2_i3 48 |
//                            y1_i0 96 | y2_i1 48 | y2_i4 48 | y2_i0 48]
__global__ __launch_bounds__(256) void k_prep(
    const float* __restrict__ node_f, const float* __restrict__ edge_f,
    const float* __restrict__ D1g, const float* __restrict__ D2g,
    const float* __restrict__ mg_g, const float* __restrict__ Wg,
    const float* __restrict__ latg, const float* __restrict__ eohg,
    const int* __restrict__ eidx, const int* __restrict__ act,
    ushort* __restrict__ f_all, float* __restrict__ gf_out,
    ushort* __restrict__ lat_bf, ushort* __restrict__ mlp2_in) {
  __shared__ float sh[4][1196];
  const int w = threadIdx.x >> 6, lane = threadIdx.x & 63;
  const int e = blockIdx.x * 4 + w;
  float* s = sh[w];
  float* s_nc = s;
  float* s_ef = s + 240;
  float* s_nn = s + 480;
  float* s_d1 = s + 720;
  float* s_d2 = s + 729;
  float* s_mg = s + 754;
  float* s_lg = s + 818;
  ushort* row = (ushort*)(s + 828);  // 736 ushorts, 16B-aligned
  const int ae = act[e];
  const int ec = eidx[ae], en = eidx[EDGES + ae];
  if (lane < 60) {
    ((float4v*)s_nc)[lane] = ((const float4v*)(node_f + (size_t)ec * 240))[lane];
    ((float4v*)s_ef)[lane] = ((const float4v*)(edge_f + (size_t)e * 240))[lane];
    ((float4v*)s_nn)[lane] = ((const float4v*)(node_f + (size_t)en * 240))[lane];
  }
  if (lane < 9)  s_d1[lane] = D1g[e * 9 + lane];
  if (lane < 25) s_d2[lane] = D2g[e * 25 + lane];
  s_mg[lane] = mg_g[e * 64 + lane];
  {
    const float* lp = latg + (size_t)ae * 128;
    float a0 = lp[2 * lane], a1 = lp[2 * lane + 1];
    ((uint*)lat_bf)[(size_t)e * 64 + lane] = (uint)f2bf(a0) | ((uint)f2bf(a1) << 16);
    const float* ep = eohg + (size_t)e * 128;
    a0 = ep[2 * lane]; a1 = ep[2 * lane + 1];
    ((uint*)mlp2_in)[(size_t)e * 128 + 64 + lane] = (uint)f2bf(a0) | ((uint)f2bf(a1) << 16);
  }
  if (lane < 8) {
    float a = 0.f;
    for (int h = 0; h < 64; ++h) a += s_mg[h] * Wg[h * 8 + lane];
    s_lg[lane] = a;
  }
  if (lane < 12) {
    float m = s_lg[0];
    for (int j = 1; j < 8; ++j) m = fmaxf(m, s_lg[j]);
    float den = 0.f;
    for (int j = 0; j < 8; ++j) den += __expf(s_lg[j] - m);
    float v = 0.f;
    if (lane < 8) v = __expf(s_lg[lane] - m) / den;
    else if (lane == 8) v = 1.f;
    gf_out[e * 12 + lane] = v;
  }
  row[lane]       = f2bf(s_nc[lane]);
  row[64 + lane]  = f2bf(s_ef[lane]);
  row[128 + lane] = f2bf(s_nn[lane]);
  if (lane < 16) row[336 + lane] = 0;  // pad f0 segment 336->352
  // y1: i=0 -> 496, i=1 -> 192, i=2 -> 352
#pragma unroll
  for (int it = 0; it < 5; ++it) {
    int q = lane + it * 64;
    if (q < 288) {
      int i = q / 96, c = q - i * 96;
      const float* src = (c < 32) ? s_nc : (c < 64) ? s_ef : s_nn;
      int base = 64 + (c & 31) * 3;
      float v = s_d1[i * 3] * src[base] + s_d1[i * 3 + 1] * src[base + 1] + s_d1[i * 3 + 2] * src[base + 2];
      int dst = (i == 0) ? 496 : (i == 1) ? 192 : 352;
      row[dst + c] = f2bf(v);
    }
  }
  // y2: i=0 -> 688, i=1 -> 592, i=2 -> 288, i=3 -> 448, i=4 -> 640
#pragma unroll
  for (int it = 0; it < 4; ++it) {
    int q = lane + it * 64;
    if (q < 240) {
      int i = q / 48, c = q - i * 48;
      const float* src = (c < 16) ? s_nc : (c < 32) ? s_ef : s_nn;
      int base = 160 + (c & 15) * 5;
      float v = s_d2[i * 5] * src[base] + s_d2[i * 5 + 1] * src[base + 1] +
                s_d2[i * 5 + 2] * src[base + 2] + s_d2[i * 5 + 3] * src[base + 3] +
                s_d2[i * 5 + 4] * src[base + 4];
      int dst = (i == 0) ? 688 : (i == 1) ? 592 : (i == 2) ? 288 : (i == 3) ? 448 : 640;
      row[dst + c] = f2bf(v);
    }
  }
  const uintx4* row4 = (const uintx4*)row;
  uintx4* dst4 = (uintx4*)(f_all + (size_t)e * 736);
#pragma unroll
  for (int it = 0; it < 2; ++it) {
    int q = lane + it * 64;
    if (q < 92) dst4[q] = row4[q];
  }
}

// ---------------- bf16 MFMA GEMM: BM=64, per-t2 DMA staging (global_load_lds) ----------------
// A LDS: 64 rows x 128B (one 64-K window), chunk ch of row r stored at slot ch^(r&7).
// B LDS: NCOL cols x 128B, same swizzle. Both filled by global_load_lds with
// inverse-swizzled per-lane global sources (LDS dest linear).
template <int KZP, int SPG, int NGRP, int NCOL, int FOFF, int ASTRIDE, bool HASBIAS, bool DOSILU>
__global__ __launch_bounds__(256) void k_gemm(
    const ushort* __restrict__ A, const ushort* __restrict__ Bt,
    const float* __restrict__ gf, const float* __restrict__ bias,
    ushort* __restrict__ outb, int ob_stride, int ob_off) {
  constexpr int NFW = NCOL / 32;       // B col-frags per wave (2-way wc split)
  constexpr int A_BYTES = 64 * 128;
  constexpr int B_BYTES = NCOL * 128;
  static_assert(NCOL % 32 == 0 && KZP % 64 == 0, "geom");
  __shared__ char sm[A_BYTES + B_BYTES + ((NGRP > 1) ? 64 * 12 * 4 : 16)];
  char* a_lds = sm;
  char* b_lds = sm + A_BYTES;
  float* gf_lds = (float*)(sm + A_BYTES + B_BYTES);
  const int tid = threadIdx.x;
  const int lane = tid & 63, w = tid >> 6;
  const int wr = w >> 1, wc = w & 1;
  const int g16 = lane >> 4;
  const int e0 = blockIdx.x * 64;
  const f32x4 vzero = {0.f, 0.f, 0.f, 0.f};

  if constexpr (NGRP > 1) {
    for (int q = tid; q < 768; q += 256)
      gf_lds[q] = gf[(size_t)(e0 + q / 12) * 12 + (q - (q / 12) * 12)];
  }

  f32x4 accS[2][NFW], accC[2][NFW];
#pragma unroll
  for (int mi = 0; mi < 2; ++mi)
#pragma unroll
    for (int n = 0; n < NFW; ++n) { accS[mi][n] = vzero; accC[mi][n] = vzero; }

  constexpr int NT2 = KZP / 64;
  for (int t2 = 0; t2 < NT2; ++t2) {
    // uniform group-local K offsets for the two 32-K halves of this window
    int ts0, ts1, gg0, gg1;
    if constexpr (NGRP > 1) {
      int tt0 = 2 * t2, tt1 = 2 * t2 + 1;
      gg0 = tt0 / SPG; ts0 = tt0 - gg0 * SPG;
      gg1 = tt1 / SPG; ts1 = tt1 - gg1 * SPG;
    } else {
      ts0 = 2 * t2; ts1 = 2 * t2 + 1; gg0 = 0; gg1 = 0;
    }
    // stage A: 512 chunks, 2 DMA instrs per wave
#pragma unroll
    for (int it = 0; it < 2; ++it) {
      int q = (w + it * 4) * 64 + lane;
      int r = q >> 3, c8 = q & 7;
      int ch = c8 ^ (r & 7);
      int tsx = (ch >> 2) ? ts1 : ts0;
      const char* gsrc = (const char*)(A + (size_t)(e0 + r) * ASTRIDE + FOFF) + tsx * 64 + (ch & 3) * 16;
      gload16(gsrc, a_lds + (w + it * 4) * 1024);
    }
    // stage B: NCOL*8 chunks, NCOL/32 DMA instrs per wave
#pragma unroll
    for (int it = 0; it < NCOL / 32; ++it) {
      int q = (w + it * 4) * 64 + lane;
      int c = q >> 3, c8 = q & 7;
      int ch = c8 ^ (c & 7);
      const char* gsrc = (const char*)(Bt + (size_t)c * KZP) + t2 * 128 + ch * 16;
      gload16(gsrc, b_lds + (w + it * 4) * 1024);
    }
    __syncthreads();
#pragma unroll
    for (int s = 0; s < 2; ++s) {
      bf16x8 a[2];
#pragma unroll
      for (int mi = 0; mi < 2; ++mi) {
        int rA = wr * 32 + mi * 16 + (lane & 15);
        int slot = (s * 4 + g16) ^ (rA & 7);
        a[mi] = *(const bf16x8*)(a_lds + rA * 128 + slot * 16);
      }
#pragma unroll
      for (int n = 0; n < NFW; ++n) {
        int cB = (wc * NFW + n) * 16 + (lane & 15);
        int slot = (s * 4 + g16) ^ (cB & 7);
        bf16x8 b = *(const bf16x8*)(b_lds + cB * 128 + slot * 16);
#pragma unroll
        for (int mi = 0; mi < 2; ++mi) {
          if constexpr (NGRP > 1)
            accC[mi][n] = __builtin_amdgcn_mfma_f32_16x16x32_bf16(a[mi], b, accC[mi][n], 0, 0, 0);
          else
            accS[mi][n] = __builtin_amdgcn_mfma_f32_16x16x32_bf16(a[mi], b, accS[mi][n], 0, 0, 0);
        }
      }
      if constexpr (NGRP > 1) {
        const int tsx = s ? ts1 : ts0;
        const int gx = s ? gg1 : gg0;
        if (tsx == SPG - 1 && gx < NGRP) {
          float g4[2][4];
#pragma unroll
          for (int mi = 0; mi < 2; ++mi)
#pragma unroll
            for (int j = 0; j < 4; ++j)
              g4[mi][j] = gf_lds[(wr * 32 + mi * 16 + g16 * 4 + j) * 12 + gx];
#pragma unroll
          for (int mi = 0; mi < 2; ++mi)
#pragma unroll
            for (int n = 0; n < NFW; ++n) {
#pragma unroll
              for (int j = 0; j < 4; ++j) accS[mi][n][j] += g4[mi][j] * accC[mi][n][j];
              accC[mi][n] = vzero;
            }
        }
      }
    }
    __syncthreads();
  }

#pragma unroll
  for (int mi = 0; mi < 2; ++mi) {
    const int row0 = wr * 32 + mi * 16 + g16 * 4;
#pragma unroll
    for (int n = 0; n < NFW; ++n) {
      const int c = (wc * NFW + n) * 16 + (lane & 15);
      float bv = 0.f;
      if constexpr (HASBIAS) bv = bias[c];
#pragma unroll
      for (int j = 0; j < 4; ++j) {
        float v = accS[mi][n][j] + bv;
        if constexpr (DOSILU) v = v / (1.f + __expf(-v));
        const int er = e0 + row0 + j;
        outb[(size_t)er * ob_stride + ob_off + c] = f2bf(v);
      }
    }
  }
}

// ---------------- post-MoE per-edge ----------------
__global__ __launch_bounds__(128) void k_post1(
    const ushort* __restrict__ moeout,
    const float* __restrict__ D1g, const float* __restrict__ D2g,
    const float* __restrict__ latg, const int* __restrict__ act,
    const float* __restrict__ P0, const float* __restrict__ b0,
    const float* __restrict__ P1, const float* __restrict__ P2,
    const ushort* __restrict__ wbuf, const float* __restrict__ beg,
    const float* __restrict__ lng, const float* __restrict__ lnb,
    float* __restrict__ new_edge, ushort* __restrict__ mlp1_in) {
  __shared__ float s0[160], s1[96], s2[32], sd1[9], sd2[25], lat[128],
      wv[112], z1r[96], z2r[80], v1p[96], v2p[80], scs[64], sps[64], sg[48], pr[4];
  const int t = threadIdx.x;
  const int e = blockIdx.x;
  const int ae = act[e];
  lat[t] = latg[ae * 128 + t];
  s0[t] = bf2f(moeout[e * 288 + t]);
  if (t < 32) s0[128 + t] = bf2f(moeout[e * 288 + 128 + t]);
  if (t < 96) s1[t] = bf2f(moeout[e * 288 + 160 + t]);
  if (t < 32) s2[t] = bf2f(moeout[e * 288 + 256 + t]);
  if (t < 9)  sd1[t] = D1g[e * 9 + t];
  if (t < 25) sd2[t] = D2g[e * 25 + t];
  if (t < 112) wv[t] = bf2f(wbuf[e * 128 + t]) + beg[t];
  __syncthreads();
  if (t < 64) { float x = s0[t]; scs[t] = x / (1.f + __expf(-x)); }
  if (t < 48) sg[t] = 1.f / (1.f + __expf(-s0[64 + t]));
  if (t < 96) {
    int c = t / 3, i = t - c * 3;
    z1r[t] = sd1[i] * s1[48 + c] + sd1[3 + i] * s0[112 + c] + sd1[6 + i] * s1[c];
  }
  if (t < 80) {
    int c = t / 5, i = t - c * 5;
    z2r[t] = sd2[i] * s2[16 + c] + sd2[5 + i] * s1[80 + c] + sd2[10 + i] * s0[144 + c] +
             sd2[15 + i] * s1[32 + c] + sd2[20 + i] * s2[c];
  }
  {
    float v = lat[t];
    float sum = v, sq = v * v;
#pragma unroll
    for (int o = 32; o > 0; o >>= 1) {
      sum += __shfl_down(sum, o);
      sq += __shfl_down(sq, o);
    }
    if ((t & 63) == 0) { pr[t >> 6] = sum; pr[2 + (t >> 6)] = sq; }
  }
  __syncthreads();
  const float mu = (pr[0] + pr[1]) * (1.f / 128.f);
  const float var = (pr[2] + pr[3]) * (1.f / 128.f) - mu * mu;
  const float rs = rsqrtf(var + 1e-5f);
  if (t < 64) {
    float a = b0[t];
    for (int c = 0; c < 64; ++c) a += scs[c] * P0[c * 64 + t];
    sps[t] = a;
    mlp1_in[e * 192 + 128 + t] = f2bf(a);
  }
  if (t < 96) {
    int d = t / 3, m = t - d * 3;
    float a = 0.f;
    for (int c = 0; c < 32; ++c) a += z1r[c * 3 + m] * sg[c] * P1[c * 32 + d];
    v1p[t] = a;
  }
  if (t < 80) {
    int d = t / 5, m = t - d * 5;
    float a = 0.f;
    for (int c = 0; c < 16; ++c) a += z2r[c * 5 + m] * sg[32 + c] * P2[c * 16 + d];
    v2p[t] = a;
  }
  {
    float ln = (lat[t] - mu) * rs * lng[t] + lnb[t];
    mlp1_in[e * 192 + t] = f2bf(ln);
  }
  __syncthreads();
  for (int d = t; d < 240; d += 128) {
    float val;
    if (d < 64) val = sps[d] * wv[d];
    else if (d < 160) { int dd = d - 64; val = v1p[dd] * wv[64 + dd / 3]; }
    else { int dd = d - 160; val = v2p[dd] * wv[96 + dd / 5]; }
    new_edge[e * 240 + d] = val;
  }
}

// ---------------- final combine ----------------
__global__ __launch_bounds__(128) void k_final(
    const ushort* __restrict__ nl2, const ushort* __restrict__ tbuf,
    const float* __restrict__ cutg, const int* __restrict__ act,
    const float* __restrict__ efg, const float* __restrict__ new_edge,
    const float* __restrict__ latg,
    float* __restrict__ out_edge, float* __restrict__ out_lat) {
  __shared__ float tv[112];
  const int t = threadIdx.x;
  const int e = blockIdx.x;
  const int ae = act[e];
  if (t < 112) tv[t] = bf2f(tbuf[e * 128 + t]) * T_SCALE;
  const float cut = cutg[ae];
  out_lat[ae * 128 + t] = C_NEW * (cut * bf2f(nl2[e * 128 + t])) + C_OLD * latg[ae * 128 + t];
  __syncthreads();
  for (int d = t; d < 240; d += 128) {
    float v = C_OLD * efg[e * 240 + d] + C_NEW * new_edge[e * 240 + d];
    float f;
    if (d < 64) f = tv[d];
    else if (d < 160) f = tv[64 + (d - 64) / 3];
    else f = tv[96 + (d - 160) / 5];
    out_edge[e * 240 + d] = v * (1.f + f);
  }
}

extern "C" void kernel_launch(void* const* d_in, const int* in_sizes, int n_in,
                              void* d_out, int out_size, void* d_ws, size_t ws_size,
                              hipStream_t stream) {
  const float* latents = (const float*)d_in[0];
  const float* node_f  = (const float*)d_in[1];
  const float* edge_f  = (const float*)d_in[3];
  const float* cutoff  = (const float*)d_in[5];
  const float* eoh     = (const float*)d_in[6];
  const float* D1      = (const float*)d_in[7];
  const float* D2      = (const float*)d_in[8];
  const float* mg      = (const float*)d_in[9];
  const int*   eidx    = (const int*)d_in[10];
  const int*   act     = (const int*)d_in[11];
  const float* Wg      = (const float*)d_in[12];
  const float* W0      = (const float*)d_in[13];
  const float* W1r     = (const float*)d_in[14];
  const float* W1i     = (const float*)d_in[15];
  const float* W2r     = (const float*)d_in[16];
  const float* W2i     = (const float*)d_in[17];
  const float* P0      = (const float*)d_in[18];
  const float* b0      = (const float*)d_in[19];
  const float* P1      = (const float*)d_in[20];
  const float* P2      = (const float*)d_in[21];
  const float* We      = (const float*)d_in[22];
  const float* be      = (const float*)d_in[23];
  const float* lng     = (const float*)d_in[24];
  const float* lnb     = (const float*)d_in[25];
  const float* M1W0_   = (const float*)d_in[26];
  const float* M1b0_   = (const float*)d_in[27];
  const float* M1W1_   = (const float*)d_in[28];
  const float* M1b1_   = (const float*)d_in[29];
  const float* M1W2_   = (const float*)d_in[30];
  const float* M1b2_   = (const float*)d_in[31];
  const float* M2W0_   = (const float*)d_in[32];
  const float* M2b0_   = (const float*)d_in[33];
  const float* M2W1_   = (const float*)d_in[34];
  const float* M2b1_   = (const float*)d_in[35];
  const float* M2W2_   = (const float*)d_in[36];
  const float* M2b2_   = (const float*)d_in[37];
  const float* T0      = (const float*)d_in[38];
  const float* T1      = (const float*)d_in[39];
  const float* T2      = (const float*)d_in[40];

  float* out_edge = (float*)d_out;
  float* out_lat  = out_edge + (size_t)EDGES * 240;
  float* out_d1   = out_lat + (size_t)EDGES * 128;
  float* out_d2   = out_d1 + (size_t)EDGES * 9;

  char* ws = (char*)d_ws;
  size_t off = 0;
  auto alloc = [&](size_t bytes) -> char* {
    char* p = ws + off;
    off += (bytes + 255) & ~size_t(255);
    return p;
  };
  ushort* f_all  = (ushort*)alloc((size_t)EDGES * 736 * 2);  // reused for MLP bufs
  float*  gfb    = (float*) alloc((size_t)EDGES * 12 * 4);
  ushort* moeout = (ushort*)alloc((size_t)EDGES * 288 * 2);
  ushort* m2in   = (ushort*)alloc((size_t)EDGES * 256 * 2);
  ushort* latbf  = (ushort*)alloc((size_t)EDGES * 128 * 2);  // reused as tbuf
  ushort* wbuf   = (ushort*)alloc((size_t)EDGES * 128 * 2);
  ushort* B0t    = (ushort*)alloc(160 * 3200 * 2);
  ushort* B1t    = (ushort*)alloc(96 * 2624 * 2);
  ushort* B2t    = (ushort*)alloc(32 * 896 * 2);
  ushort* Wt1    = (ushort*)alloc(128 * 192 * 2);
  ushort* Wt2    = (ushort*)alloc(128 * 128 * 2);
  ushort* Wt3    = (ushort*)alloc(128 * 128 * 2);
  ushort* Wt4    = (ushort*)alloc(128 * 256 * 2);
  ushort* Wt5    = (ushort*)alloc(128 * 128 * 2);
  ushort* Wt6    = (ushort*)alloc(128 * 128 * 2);
  ushort* Wet    = (ushort*)alloc(128 * 128 * 2);
  ushort* Ttb    = (ushort*)alloc(128 * 128 * 2);

  // overlays inside the (dead-after-MoE) f_all region: 192+128+128+128 = 576 <= 736
  ushort* m1in = f_all;
  ushort* h1   = f_all + (size_t)EDGES * 192;
  ushort* h2   = f_all + (size_t)EDGES * 320;
  ushort* nl2  = f_all + (size_t)EDGES * 448;
  ushort* tbuf = latbf;

  hipMemcpyAsync(out_lat, (const void*)latents, (size_t)EDGES * 128 * 4, hipMemcpyDeviceToDevice, stream);
  hipMemcpyAsync(out_d1, (const void*)D1, (size_t)EDGES * 9 * 4, hipMemcpyDeviceToDevice, stream);
  hipMemcpyAsync(out_d2, (const void*)D2, (size_t)EDGES * 25 * 4, hipMemcpyDeviceToDevice, stream);

  if (ws_size < off) return;

  k_pack_b0<<<2000, 256, 0, stream>>>(W0, B0t);
  k_pack_b1<<<984, 256, 0, stream>>>(W1r, W1i, B1t);
  k_pack_b2<<<112, 256, 0, stream>>>(W2r, W2i, B2t);
  PackPtrs pp = {M1W0_, M1W1_, M1W2_, M2W0_, M2W1_, M2W2_, We, T0, T1, T2,
                 Wt1, Wt2, Wt3, Wt4, Wt5, Wt6, Wet, Ttb};
  k_pack_small<<<608, 256, 0, stream>>>(pp);

  k_prep<<<EDGES / 4, 256, 0, stream>>>(node_f, edge_f, D1, D2, mg, Wg, latents, eoh,
                                        eidx, act, f_all, gfb, latbf, m2in);

  // MoE GEMMs -> bf16 moeout [0:160|160:256|256:288]
  k_gemm<3200, 11, 9, 160, 0, 736, false, false>
      <<<1024, 256, 0, stream>>>(f_all, B0t, gfb, nullptr, moeout, 288, 0);
  k_gemm<2624, 9, 9, 96, 352, 736, false, false>
      <<<1024, 256, 0, stream>>>(f_all, B1t, gfb, nullptr, moeout, 288, 160);
  k_gemm<896, 3, 9, 32, 640, 736, false, false>
      <<<1024, 256, 0, stream>>>(f_all, B2t, gfb, nullptr, moeout, 288, 256);

  // lat @ We ; eoh @ T^T (reads m2in[:,128:], writes tbuf == latbf region)
  k_gemm<128, 4, 1, 128, 0, 128, false, false>
      <<<1024, 256, 0, stream>>>(latbf, Wet, nullptr, nullptr, wbuf, 128, 0);
  k_gemm<128, 4, 1, 128, 128, 256, false, false>
      <<<1024, 256, 0, stream>>>(m2in, Ttb, nullptr, nullptr, tbuf, 128, 0);

  // new_edge staged directly in d_out edge region
  k_post1<<<EDGES, 128, 0, stream>>>(moeout, D1, D2, latents, act,
                                     P0, b0, P1, P2, wbuf, be, lng, lnb, out_edge, m1in);

  // MLP1: 192->128 silu, 128->128 silu, 128->128 (into m2in[:,0:128])
  k_gemm<192, 6, 1, 128, 0, 192, true, true>
      <<<1024, 256, 0, stream>>>(m1in, Wt1, nullptr, M1b0_, h1, 128, 0);
  k_gemm<128, 4, 1, 128, 0, 128, true, true>
      <<<1024, 256, 0, stream>>>(h1, Wt2, nullptr, M1b1_, h2, 128, 0);
  k_gemm<128, 4, 1, 128, 0, 128, true, false>
      <<<1024, 256, 0, stream>>>(h2, Wt3, nullptr, M1b2_, m2in, 256, 0);
  // MLP2: 256->128 silu, 128->128 silu, 128->128 -> nl2 (bf16)
  k_gemm<256, 8, 1, 128, 0, 256, true, true>
      <<<1024, 256, 0, stream>>>(m2in, Wt4, nullptr, M2b0_, h1, 128, 0);
  k_gemm<128, 4, 1, 128, 0, 128, true, true>
      <<<1024, 256, 0, stream>>>(h1, Wt5, nullptr, M2b1_, h2, 128, 0);
  k_gemm<128, 4, 1, 128, 0, 128, true, false>
      <<<1024, 256, 0, stream>>>(h2, Wt6, nullptr, M2b2_, nl2, 128, 0);

  k_final<<<EDGES, 128, 0, stream>>>(nl2, tbuf, cutoff, act, edge_f, out_edge, latents,
                                     out_edge, out_lat);
}

// Round 5
// 589.225 us; speedup vs baseline: 1.5813x; 1.1070x over previous
//
#include <hip/hip_runtime.h>
#include <hip/hip_bf16.h>
#include <stdint.h>

#define EDGES 65536

typedef unsigned int uint;
typedef unsigned short ushort;
using bf16x8 = __attribute__((ext_vector_type(8))) __bf16;
using f32x4  = __attribute__((ext_vector_type(4))) float;
using uintx4 = __attribute__((ext_vector_type(4))) uint;
using float4v = __attribute__((ext_vector_type(4))) float;

#define C_OLD 0.8944271909999159f
#define C_NEW 0.4472135954999579f
#define T_SCALE 0.08838834764831845f

__device__ __forceinline__ ushort f2bf(float f) {
  uint x = __builtin_bit_cast(uint, f);
  uint r = x + 0x7FFFu + ((x >> 16) & 1u);
  return (ushort)(r >> 16);
}
__device__ __forceinline__ float bf2f(ushort u) {
  uint x = (uint)u << 16;
  return __builtin_bit_cast(float, x);
}
__device__ __forceinline__ void gload16(const void* g, void* l) {
  __builtin_amdgcn_global_load_lds(
      (const __attribute__((address_space(1))) void*)g,
      (__attribute__((address_space(3))) void*)l, 16, 0, 0);
}

// ---------------- weight pack kernels ----------------
__global__ __launch_bounds__(256) void k_pack_b0(const float* __restrict__ W0, ushort* __restrict__ B) {
  int idx = blockIdx.x * 256 + threadIdx.x;
  if (idx >= 160 * 3200) return;
  int o = idx / 3200, kf = idx - o * 3200;
  int k = kf / 352, f = kf - k * 352;
  float v = (k < 9 && f < 336) ? W0[k * 53760 + f * 160 + o] : 0.f;
  B[idx] = f2bf(v);
}
__global__ __launch_bounds__(256) void k_pack_b1(const float* __restrict__ Wr, const float* __restrict__ Wi, ushort* __restrict__ B) {
  int idx = blockIdx.x * 256 + threadIdx.x;
  if (idx >= 96 * 2624) return;
  int c = idx / 2624, kf = idx - c * 2624;
  int k = kf / 288, f = kf - k * 288;
  float v = 0.f;
  if (k < 9) {
    if (c < 48) v = (f < 144) ? Wr[k * 6912 + f * 48 + c] : -Wi[k * 6912 + (f - 144) * 48 + c];
    else        v = (f < 144) ? Wi[k * 6912 + f * 48 + (c - 48)] : Wr[k * 6912 + (f - 144) * 48 + (c - 48)];
  }
  B[idx] = f2bf(v);
}
__global__ __launch_bounds__(256) void k_pack_b2(const float* __restrict__ Wr, const float* __restrict__ Wi, ushort* __restrict__ B) {
  int idx = blockIdx.x * 256 + threadIdx.x;
  if (idx >= 32 * 896) return;
  int c = idx / 896, kf = idx - c * 896;
  int k = kf / 96, f = kf - k * 96;
  float v = 0.f;
  if (k < 9) {
    if (c < 16) v = (f < 48) ? Wr[k * 768 + f * 16 + c] : -Wi[k * 768 + (f - 48) * 16 + c];
    else        v = (f < 48) ? Wi[k * 768 + f * 16 + (c - 16)] : Wr[k * 768 + (f - 48) * 16 + (c - 16)];
  }
  B[idx] = f2bf(v);
}
struct PackPtrs {
  const float *s0, *s1, *s2, *s3, *s4, *s5, *we, *t0, *t1, *t2, *p0;
  ushort *d0, *d1, *d2, *d3, *d4, *d5, *dwe, *dtt, *dp0;
};
__global__ __launch_bounds__(256) void k_pack_small(PackPtrs p) {
  int idx = blockIdx.x * 256 + threadIdx.x;
  if (idx < 24576) {
    int n = idx / 192, k = idx - n * 192;
    p.d0[idx] = f2bf(p.s0[k * 128 + n]);
  } else if (idx < 40960) {
    int q = idx - 24576; int n = q >> 7, k = q & 127;
    p.d1[q] = f2bf(p.s1[k * 128 + n]);
  } else if (idx < 57344) {
    int q = idx - 40960; int n = q >> 7, k = q & 127;
    p.d2[q] = f2bf(p.s2[k * 128 + n]);
  } else if (idx < 90112) {
    int q = idx - 57344; int n = q / 256, k = q - n * 256;
    p.d3[q] = f2bf(p.s3[k * 128 + n]);
  } else if (idx < 106496) {
    int q = idx - 90112; int n = q >> 7, k = q & 127;
    p.d4[q] = f2bf(p.s4[k * 128 + n]);
  } else if (idx < 122880) {
    int q = idx - 106496; int n = q >> 7, k = q & 127;
    p.d5[q] = f2bf(p.s5[k * 128 + n]);
  } else if (idx < 139264) {
    int q = idx - 122880; int n = q >> 7, k = q & 127;
    p.dwe[q] = f2bf((n < 112) ? p.we[k * 112 + n] : 0.f);
  } else if (idx < 155648) {
    int q = idx - 139264; int o = q >> 7, h = q & 127;
    float v = 0.f;
    if (o < 64) v = p.t0[o * 128 + h];
    else if (o < 96) v = p.t1[(o - 64) * 128 + h];
    else if (o < 112) v = p.t2[(o - 96) * 128 + h];
    p.dtt[q] = f2bf(v);
  } else if (idx < 159744) {  // P0t: Bt[n*64+k] = P0[k*64+n]
    int q = idx - 155648; int n = q >> 6, k = q & 63;
    p.dp0[q] = f2bf(p.p0[k * 64 + n]);
  }
}

// ---------------- prep: gather + Wigner rotate + softmax gates (wave-per-edge) ----------------
__global__ __launch_bounds__(256) void k_prep(
    const float* __restrict__ node_f, const float* __restrict__ edge_f,
    const float* __restrict__ D1g, const float* __restrict__ D2g,
    const float* __restrict__ mg_g, const float* __restrict__ Wg,
    const float* __restrict__ latg, const float* __restrict__ eohg,
    const int* __restrict__ eidx, const int* __restrict__ act,
    ushort* __restrict__ f_all, float* __restrict__ gf_out,
    ushort* __restrict__ lat_bf, ushort* __restrict__ mlp2_in) {
  __shared__ float sh[4][1196];
  const int w = threadIdx.x >> 6, lane = threadIdx.x & 63;
  const int e = blockIdx.x * 4 + w;
  float* s = sh[w];
  float* s_nc = s;
  float* s_ef = s + 240;
  float* s_nn = s + 480;
  float* s_d1 = s + 720;
  float* s_d2 = s + 729;
  float* s_mg = s + 754;
  float* s_lg = s + 818;
  ushort* row = (ushort*)(s + 828);
  const int ae = act[e];
  const int ec = eidx[ae], en = eidx[EDGES + ae];
  if (lane < 60) {
    ((float4v*)s_nc)[lane] = ((const float4v*)(node_f + (size_t)ec * 240))[lane];
    ((float4v*)s_ef)[lane] = ((const float4v*)(edge_f + (size_t)e * 240))[lane];
    ((float4v*)s_nn)[lane] = ((const float4v*)(node_f + (size_t)en * 240))[lane];
  }
  if (lane < 9)  s_d1[lane] = D1g[e * 9 + lane];
  if (lane < 25) s_d2[lane] = D2g[e * 25 + lane];
  s_mg[lane] = mg_g[e * 64 + lane];
  {
    const float* lp = latg + (size_t)ae * 128;
    float a0 = lp[2 * lane], a1 = lp[2 * lane + 1];
    ((uint*)lat_bf)[(size_t)e * 64 + lane] = (uint)f2bf(a0) | ((uint)f2bf(a1) << 16);
    const float* ep = eohg + (size_t)e * 128;
    a0 = ep[2 * lane]; a1 = ep[2 * lane + 1];
    ((uint*)mlp2_in)[(size_t)e * 128 + 64 + lane] = (uint)f2bf(a0) | ((uint)f2bf(a1) << 16);
  }
  if (lane < 8) {
    float a = 0.f;
    for (int h = 0; h < 64; ++h) a += s_mg[h] * Wg[h * 8 + lane];
    s_lg[lane] = a;
  }
  if (lane < 12) {
    float m = s_lg[0];
    for (int j = 1; j < 8; ++j) m = fmaxf(m, s_lg[j]);
    float den = 0.f;
    for (int j = 0; j < 8; ++j) den += __expf(s_lg[j] - m);
    float v = 0.f;
    if (lane < 8) v = __expf(s_lg[lane] - m) / den;
    else if (lane == 8) v = 1.f;
    gf_out[e * 12 + lane] = v;
  }
  row[lane]       = f2bf(s_nc[lane]);
  row[64 + lane]  = f2bf(s_ef[lane]);
  row[128 + lane] = f2bf(s_nn[lane]);
  if (lane < 16) row[336 + lane] = 0;
#pragma unroll
  for (int it = 0; it < 5; ++it) {
    int q = lane + it * 64;
    if (q < 288) {
      int i = q / 96, c = q - i * 96;
      const float* src = (c < 32) ? s_nc : (c < 64) ? s_ef : s_nn;
      int base = 64 + (c & 31) * 3;
      float v = s_d1[i * 3] * src[base] + s_d1[i * 3 + 1] * src[base + 1] + s_d1[i * 3 + 2] * src[base + 2];
      int dst = (i == 0) ? 496 : (i == 1) ? 192 : 352;
      row[dst + c] = f2bf(v);
    }
  }
#pragma unroll
  for (int it = 0; it < 4; ++it) {
    int q = lane + it * 64;
    if (q < 240) {
      int i = q / 48, c = q - i * 48;
      const float* src = (c < 16) ? s_nc : (c < 32) ? s_ef : s_nn;
      int base = 160 + (c & 15) * 5;
      float v = s_d2[i * 5] * src[base] + s_d2[i * 5 + 1] * src[base + 1] +
                s_d2[i * 5 + 2] * src[base + 2] + s_d2[i * 5 + 3] * src[base + 3] +
                s_d2[i * 5 + 4] * src[base + 4];
      int dst = (i == 0) ? 688 : (i == 1) ? 592 : (i == 2) ? 288 : (i == 3) ? 448 : 640;
      row[dst + c] = f2bf(v);
    }
  }
  const uintx4* row4 = (const uintx4*)row;
  uintx4* dst4 = (uintx4*)(f_all + (size_t)e * 736);
#pragma unroll
  for (int it = 0; it < 2; ++it) {
    int q = lane + it * 64;
    if (q < 92) dst4[q] = row4[q];
  }
}

// ---------------- bf16 MFMA GEMM: BM=64, per-t2 DMA staging ----------------
// EPI: 0=raw bf16, 1=silu bf16, 2=raw + silu(c<64) to outb2 (stride 256), 3=lat-update f32
template <int KZP, int SPG, int NGRP, int NCOL, int FOFF, int ASTRIDE, bool HASBIAS, int EPI>
__global__ __launch_bounds__(256) void k_gemm(
    const ushort* __restrict__ A, const ushort* __restrict__ Bt,
    const float* __restrict__ gf, const float* __restrict__ bias,
    ushort* __restrict__ outb, int ob_stride, int ob_off,
    ushort* __restrict__ outb2, float* __restrict__ outf,
    const int* __restrict__ act, const float* __restrict__ cutg,
    const float* __restrict__ latg) {
  constexpr int NFW = NCOL / 32;
  constexpr int A_BYTES = 64 * 128;
  constexpr int B_BYTES = NCOL * 128;
  static_assert(NCOL % 32 == 0 && KZP % 64 == 0, "geom");
  __shared__ char sm[A_BYTES + B_BYTES + ((NGRP > 1) ? 64 * 12 * 4 : 16)];
  char* a_lds = sm;
  char* b_lds = sm + A_BYTES;
  float* gf_lds = (float*)(sm + A_BYTES + B_BYTES);
  const int tid = threadIdx.x;
  const int lane = tid & 63, w = tid >> 6;
  const int wr = w >> 1, wc = w & 1;
  const int g16 = lane >> 4;
  const int e0 = blockIdx.x * 64;
  const f32x4 vzero = {0.f, 0.f, 0.f, 0.f};

  if constexpr (NGRP > 1) {
    for (int q = tid; q < 768; q += 256)
      gf_lds[q] = gf[(size_t)(e0 + q / 12) * 12 + (q - (q / 12) * 12)];
  }

  f32x4 accS[2][NFW], accC[2][NFW];
#pragma unroll
  for (int mi = 0; mi < 2; ++mi)
#pragma unroll
    for (int n = 0; n < NFW; ++n) { accS[mi][n] = vzero; accC[mi][n] = vzero; }

  constexpr int NT2 = KZP / 64;
  for (int t2 = 0; t2 < NT2; ++t2) {
    int ts0, ts1, gg0, gg1;
    if constexpr (NGRP > 1) {
      int tt0 = 2 * t2, tt1 = 2 * t2 + 1;
      gg0 = tt0 / SPG; ts0 = tt0 - gg0 * SPG;
      gg1 = tt1 / SPG; ts1 = tt1 - gg1 * SPG;
    } else {
      ts0 = 2 * t2; ts1 = 2 * t2 + 1; gg0 = 0; gg1 = 0;
    }
#pragma unroll
    for (int it = 0; it < 2; ++it) {
      int q = (w + it * 4) * 64 + lane;
      int r = q >> 3, c8 = q & 7;
      int ch = c8 ^ (r & 7);
      int tsx = (ch >> 2) ? ts1 : ts0;
      const char* gsrc = (const char*)(A + (size_t)(e0 + r) * ASTRIDE + FOFF) + tsx * 64 + (ch & 3) * 16;
      gload16(gsrc, a_lds + (w + it * 4) * 1024);
    }
#pragma unroll
    for (int it = 0; it < NCOL / 32; ++it) {
      int q = (w + it * 4) * 64 + lane;
      int c = q >> 3, c8 = q & 7;
      int ch = c8 ^ (c & 7);
      const char* gsrc = (const char*)(Bt + (size_t)c * KZP) + t2 * 128 + ch * 16;
      gload16(gsrc, b_lds + (w + it * 4) * 1024);
    }
    __syncthreads();
#pragma unroll
    for (int s = 0; s < 2; ++s) {
      bf16x8 a[2];
#pragma unroll
      for (int mi = 0; mi < 2; ++mi) {
        int rA = wr * 32 + mi * 16 + (lane & 15);
        int slot = (s * 4 + g16) ^ (rA & 7);
        a[mi] = *(const bf16x8*)(a_lds + rA * 128 + slot * 16);
      }
#pragma unroll
      for (int n = 0; n < NFW; ++n) {
        int cB = (wc * NFW + n) * 16 + (lane & 15);
        int slot = (s * 4 + g16) ^ (cB & 7);
        bf16x8 b = *(const bf16x8*)(b_lds + cB * 128 + slot * 16);
#pragma unroll
        for (int mi = 0; mi < 2; ++mi) {
          if constexpr (NGRP > 1)
            accC[mi][n] = __builtin_amdgcn_mfma_f32_16x16x32_bf16(a[mi], b, accC[mi][n], 0, 0, 0);
          else
            accS[mi][n] = __builtin_amdgcn_mfma_f32_16x16x32_bf16(a[mi], b, accS[mi][n], 0, 0, 0);
        }
      }
      if constexpr (NGRP > 1) {
        const int tsx = s ? ts1 : ts0;
        const int gx = s ? gg1 : gg0;
        if (tsx == SPG - 1 && gx < NGRP) {
          float g4[2][4];
#pragma unroll
          for (int mi = 0; mi < 2; ++mi)
#pragma unroll
            for (int j = 0; j < 4; ++j)
              g4[mi][j] = gf_lds[(wr * 32 + mi * 16 + g16 * 4 + j) * 12 + gx];
#pragma unroll
          for (int mi = 0; mi < 2; ++mi)
#pragma unroll
            for (int n = 0; n < NFW; ++n) {
#pragma unroll
              for (int j = 0; j < 4; ++j) accS[mi][n][j] += g4[mi][j] * accC[mi][n][j];
              accC[mi][n] = vzero;
            }
        }
      }
    }
    __syncthreads();
  }

#pragma unroll
  for (int mi = 0; mi < 2; ++mi) {
    const int row0 = wr * 32 + mi * 16 + g16 * 4;
#pragma unroll
    for (int n = 0; n < NFW; ++n) {
      const int c = (wc * NFW + n) * 16 + (lane & 15);
      float bv = 0.f;
      if constexpr (HASBIAS) bv = bias[c];
#pragma unroll
      for (int j = 0; j < 4; ++j) {
        float v = accS[mi][n][j] + bv;
        const int er = e0 + row0 + j;
        if constexpr (EPI == 1) v = v / (1.f + __expf(-v));
        if constexpr (EPI == 3) {
          int ae = act[er];
          outf[(size_t)ae * 128 + c] = C_NEW * cutg[ae] * v + C_OLD * latg[(size_t)ae * 128 + c];
        } else {
          outb[(size_t)er * ob_stride + ob_off + c] = f2bf(v);
          if constexpr (EPI == 2) {
            if ((wc * NFW + n) * 16 < 64)
              outb2[(size_t)er * 256 + c] = f2bf(v / (1.f + __expf(-v)));
          }
        }
      }
    }
  }
}

// ---------------- post-MoE: 8 edges/block, LDS-staged P1/P2 ----------------
__global__ __launch_bounds__(256) void k_post1(
    const ushort* __restrict__ moeout,
    const float* __restrict__ D1g, const float* __restrict__ D2g,
    const float* __restrict__ latg, const int* __restrict__ act,
    const float* __restrict__ P1, const float* __restrict__ P2,
    const ushort* __restrict__ wbuf, const float* __restrict__ beg,
    const float* __restrict__ lng, const float* __restrict__ lnb,
    ushort* __restrict__ m1in, float* __restrict__ new_edge) {
  __shared__ float SM[7488];
  float* sP1 = SM;            // 1024 (transposed, c-group rotated by d)
  float* sP2 = SM + 1024;     // 256
  float* be_s = SM + 1280;    // 112
  float* lng_s = SM + 1392;   // 128
  float* lnb_s = SM + 1520;   // 128
  float* sO   = SM + 1648;    // 8*224  (moeout cols 64..287)
  float* sLat = SM + 3440;    // 8*128
  float* sWv  = SM + 4464;    // 8*112 (raw, be added at use)
  float* sU1  = SM + 5360;    // 8*96  (m*32+c)
  float* sU2  = SM + 6128;    // 8*80  (m*16+c)
  float* sSg  = SM + 6768;    // 8*48
  float* sD1  = SM + 7152;    // 8*12
  float* sD2  = SM + 7248;    // 8*28
  float* sMu  = SM + 7472;    // 8
  float* sRs  = SM + 7480;    // 8
  const int t = threadIdx.x;
  const int e8 = blockIdx.x * 8;

  // ---- phase 0: loads ----
  for (int q = t; q < 368; q += 256) {
    if (q < 112) be_s[q] = beg[q];
    else if (q < 240) lng_s[q - 112] = lng[q - 112];
    else lnb_s[q - 240] = lnb[q - 240];
  }
  for (int q = t; q < 1024; q += 256) {
    int d = q >> 5, c = q & 31;
    sP1[d * 32 + ((((c >> 2) + d) & 7) << 2) + (c & 3)] = P1[c * 32 + d];
  }
  {
    int d = t >> 4, c = t & 15;
    if (t < 256) sP2[d * 16 + ((((c >> 2) + d) & 3) << 2) + (c & 3)] = P2[c * 16 + d];
  }
  {  // sO: 8 edges x 28 chunks of 8 bf16
    int e = t >> 5, kq = t & 31;
    if (kq < 28) {
      uintx4 raw = *(const uintx4*)(moeout + (size_t)(e8 + e) * 288 + 64 + kq * 8);
      float* d = sO + e * 224 + kq * 8;
#pragma unroll
      for (int j = 0; j < 4; ++j) {
        uint u = raw[j];
        d[2 * j] = bf2f((ushort)(u & 0xFFFF));
        d[2 * j + 1] = bf2f((ushort)(u >> 16));
      }
    }
  }
  {  // sLat
    int e = t >> 5, i = t & 31;
    int ae = act[e8 + e];
    ((float4v*)(sLat + e * 128))[i] = ((const float4v*)(latg + (size_t)ae * 128))[i];
  }
  {  // sWv raw
    int e = t >> 4, kq = t & 15;
    if (e < 8 && kq < 14) {
      uintx4 raw = *(const uintx4*)(wbuf + (size_t)(e8 + e) * 128 + kq * 8);
      float* d = sWv + e * 112 + kq * 8;
#pragma unroll
      for (int j = 0; j < 4; ++j) {
        uint u = raw[j];
        d[2 * j] = bf2f((ushort)(u & 0xFFFF));
        d[2 * j + 1] = bf2f((ushort)(u >> 16));
      }
    }
  }
  for (int q = t; q < 512; q += 256) {
    int e = q >> 6, i = q & 63;
    if (i < 9) sD1[e * 12 + i] = D1g[(size_t)(e8 + e) * 9 + i];
    else if (i < 34) sD2[e * 28 + (i - 9)] = D2g[(size_t)(e8 + e) * 25 + (i - 9)];
  }
  __syncthreads();

  // ---- phase 1: gates ----
  for (int q = t; q < 384; q += 256) {
    int e = q / 48, c = q - (q / 48) * 48;
    sSg[e * 48 + c] = 1.f / (1.f + __expf(-sO[e * 224 + c]));
  }
  __syncthreads();

  // ---- phase 2: u1/u2 (gated rotations) + LN reduce ----
  for (int q = t; q < 768; q += 256) {
    int e = q / 96, r = q - (q / 96) * 96;
    int m = r >> 5, c = r & 31;
    const float* o = sO + e * 224;
    const float* d1 = sD1 + e * 12;
    float v = d1[m] * o[144 + c] + d1[3 + m] * o[48 + c] + d1[6 + m] * o[96 + c];
    sU1[e * 96 + m * 32 + c] = v * sSg[e * 48 + c];
  }
  for (int q = t; q < 640; q += 256) {
    int e = q / 80, r = q - (q / 80) * 80;
    int m = r >> 4, c = r & 15;
    const float* o = sO + e * 224;
    const float* d2 = sD2 + e * 28;
    float v = d2[m] * o[208 + c] + d2[5 + m] * o[176 + c] + d2[10 + m] * o[80 + c] +
              d2[15 + m] * o[128 + c] + d2[20 + m] * o[192 + c];
    sU2[e * 80 + m * 16 + c] = v * sSg[e * 48 + 32 + c];
  }
  {
    int eg = t >> 5, l = t & 31;
    const float* lt = sLat + eg * 128;
    float v0 = lt[l], v1 = lt[l + 32], v2 = lt[l + 64], v3 = lt[l + 96];
    float sum = v0 + v1 + v2 + v3;
    float sq = v0 * v0 + v1 * v1 + v2 * v2 + v3 * v3;
#pragma unroll
    for (int m = 16; m > 0; m >>= 1) {
      sum += __shfl_xor(sum, m);
      sq += __shfl_xor(sq, m);
    }
    if (l == 0) {
      float mu = sum * (1.f / 128.f);
      float var = sq * (1.f / 128.f) - mu * mu;
      sMu[eg] = mu;
      sRs[eg] = rsqrtf(var + 1e-5f);
    }
  }
  __syncthreads();

  // ---- phase 3: P-mixes -> new_edge, LN -> m1in, sps -> new_edge ----
  for (int q = t; q < 768; q += 256) {  // v1
    int e = q / 96, r = q - (q / 96) * 96;
    int m = r >> 5, d = r & 31;
    const float* u = sU1 + e * 96 + m * 32;
    float acc = 0.f;
#pragma unroll
    for (int cq = 0; cq < 8; ++cq) {
      float4v p = *(const float4v*)(sP1 + d * 32 + (((cq + d) & 7) << 2));
      float4v uu = *(const float4v*)(u + cq * 4);
      acc += p[0] * uu[0] + p[1] * uu[1] + p[2] * uu[2] + p[3] * uu[3];
    }
    new_edge[(size_t)(e8 + e) * 240 + 64 + d * 3 + m] = acc * (sWv[e * 112 + 64 + d] + be_s[64 + d]);
  }
  for (int q = t; q < 640; q += 256) {  // v2
    int e = q / 80, r = q - (q / 80) * 80;
    int m = r >> 4, d = r & 15;
    const float* u = sU2 + e * 80 + m * 16;
    float acc = 0.f;
#pragma unroll
    for (int cq = 0; cq < 4; ++cq) {
      float4v p = *(const float4v*)(sP2 + d * 16 + (((cq + d) & 3) << 2));
      float4v uu = *(const float4v*)(u + cq * 4);
      acc += p[0] * uu[0] + p[1] * uu[1] + p[2] * uu[2] + p[3] * uu[3];
    }
    new_edge[(size_t)(e8 + e) * 240 + 160 + d * 5 + m] = acc * (sWv[e * 112 + 96 + d] + be_s[96 + d]);
  }
  for (int q = t; q < 512; q += 256) {  // sps part (read back from m1in)
    int e = q >> 6, d = q & 63;
    float sp = bf2f(m1in[(size_t)(e8 + e) * 192 + 128 + d]);
    new_edge[(size_t)(e8 + e) * 240 + d] = sp * (sWv[e * 112 + d] + be_s[d]);
  }
  for (int q = t; q < 512; q += 256) {  // LN -> m1in cols 0..127 (packed pairs)
    int e = q >> 6, i2 = q & 63;
    const float* lt = sLat + e * 128;
    float mu = sMu[e], rs = sRs[e];
    int i = 2 * i2;
    float l0 = (lt[i] - mu) * rs * lng_s[i] + lnb_s[i];
    float l1 = (lt[i + 1] - mu) * rs * lng_s[i + 1] + lnb_s[i + 1];
    ((uint*)m1in)[(size_t)(e8 + e) * 96 + i2] = (uint)f2bf(l0) | ((uint)f2bf(l1) << 16);
  }
}

// ---------------- final combine (edge part only) ----------------
__global__ __launch_bounds__(128) void k_final(
    const ushort* __restrict__ tbuf,
    const float* __restrict__ efg, const float* __restrict__ new_edge,
    float* __restrict__ out_edge) {
  __shared__ float tv[112];
  const int t = threadIdx.x;
  const int e = blockIdx.x;
  if (t < 112) tv[t] = bf2f(tbuf[e * 128 + t]) * T_SCALE;
  __syncthreads();
  for (int d = t; d < 240; d += 128) {
    float v = C_OLD * efg[(size_t)e * 240 + d] + C_NEW * new_edge[(size_t)e * 240 + d];
    float f;
    if (d < 64) f = tv[d];
    else if (d < 160) f = tv[64 + (d - 64) / 3];
    else f = tv[96 + (d - 160) / 5];
    out_edge[(size_t)e * 240 + d] = v * (1.f + f);
  }
}

extern "C" void kernel_launch(void* const* d_in, const int* in_sizes, int n_in,
                              void* d_out, int out_size, void* d_ws, size_t ws_size,
                              hipStream_t stream) {
  const float* latents = (const float*)d_in[0];
  const float* node_f  = (const float*)d_in[1];
  const float* edge_f  = (const float*)d_in[3];
  const float* cutoff  = (const float*)d_in[5];
  const float* eoh     = (const float*)d_in[6];
  const float* D1      = (const float*)d_in[7];
  const float* D2      = (const float*)d_in[8];
  const float* mg      = (const float*)d_in[9];
  const int*   eidx    = (const int*)d_in[10];
  const int*   act     = (const int*)d_in[11];
  const float* Wg      = (const float*)d_in[12];
  const float* W0      = (const float*)d_in[13];
  const float* W1r     = (const float*)d_in[14];
  const float* W1i     = (const float*)d_in[15];
  const float* W2r     = (const float*)d_in[16];
  const float* W2i     = (const float*)d_in[17];
  const float* P0      = (const float*)d_in[18];
  const float* b0      = (const float*)d_in[19];
  const float* P1      = (const float*)d_in[20];
  const float* P2      = (const float*)d_in[21];
  const float* We      = (const float*)d_in[22];
  const float* be      = (const float*)d_in[23];
  const float* lng     = (const float*)d_in[24];
  const float* lnb     = (const float*)d_in[25];
  const float* M1W0_   = (const float*)d_in[26];
  const float* M1b0_   = (const float*)d_in[27];
  const float* M1W1_   = (const float*)d_in[28];
  const float* M1b1_   = (const float*)d_in[29];
  const float* M1W2_   = (const float*)d_in[30];
  const float* M1b2_   = (const float*)d_in[31];
  const float* M2W0_   = (const float*)d_in[32];
  const float* M2b0_   = (const float*)d_in[33];
  const float* M2W1_   = (const float*)d_in[34];
  const float* M2b1_   = (const float*)d_in[35];
  const float* M2W2_   = (const float*)d_in[36];
  const float* M2b2_   = (const float*)d_in[37];
  const float* T0      = (const float*)d_in[38];
  const float* T1      = (const float*)d_in[39];
  const float* T2      = (const float*)d_in[40];

  float* out_edge = (float*)d_out;
  float* out_lat  = out_edge + (size_t)EDGES * 240;
  float* out_d1   = out_lat + (size_t)EDGES * 128;
  float* out_d2   = out_d1 + (size_t)EDGES * 9;

  char* ws = (char*)d_ws;
  size_t off = 0;
  auto alloc = [&](size_t bytes) -> char* {
    char* p = ws + off;
    off += (bytes + 255) & ~size_t(255);
    return p;
  };
  ushort* f_all  = (ushort*)alloc((size_t)EDGES * 736 * 2);
  float*  gfb    = (float*) alloc((size_t)EDGES * 12 * 4);
  ushort* moeout = (ushort*)alloc((size_t)EDGES * 288 * 2);
  ushort* m2in   = (ushort*)alloc((size_t)EDGES * 256 * 2);
  ushort* latbf  = (ushort*)alloc((size_t)EDGES * 128 * 2);
  ushort* wbuf   = (ushort*)alloc((size_t)EDGES * 128 * 2);
  ushort* B0t    = (ushort*)alloc(160 * 3200 * 2);
  ushort* B1t    = (ushort*)alloc(96 * 2624 * 2);
  ushort* B2t    = (ushort*)alloc(32 * 896 * 2);
  ushort* Wt1    = (ushort*)alloc(128 * 192 * 2);
  ushort* Wt2    = (ushort*)alloc(128 * 128 * 2);
  ushort* Wt3    = (ushort*)alloc(128 * 128 * 2);
  ushort* Wt4    = (ushort*)alloc(128 * 256 * 2);
  ushort* Wt5    = (ushort*)alloc(128 * 128 * 2);
  ushort* Wt6    = (ushort*)alloc(128 * 128 * 2);
  ushort* Wet    = (ushort*)alloc(128 * 128 * 2);
  ushort* Ttb    = (ushort*)alloc(128 * 128 * 2);
  ushort* P0t    = (ushort*)alloc(64 * 64 * 2);

  ushort* m1in = f_all;
  ushort* h1   = f_all + (size_t)EDGES * 192;
  ushort* h2   = f_all + (size_t)EDGES * 320;
  ushort* tbuf = latbf;

  hipMemcpyAsync(out_lat, (const void*)latents, (size_t)EDGES * 128 * 4, hipMemcpyDeviceToDevice, stream);
  hipMemcpyAsync(out_d1, (const void*)D1, (size_t)EDGES * 9 * 4, hipMemcpyDeviceToDevice, stream);
  hipMemcpyAsync(out_d2, (const void*)D2, (size_t)EDGES * 25 * 4, hipMemcpyDeviceToDevice, stream);

  if (ws_size < off) return;

  k_pack_b0<<<2000, 256, 0, stream>>>(W0, B0t);
  k_pack_b1<<<984, 256, 0, stream>>>(W1r, W1i, B1t);
  k_pack_b2<<<112, 256, 0, stream>>>(W2r, W2i, B2t);
  PackPtrs pp = {M1W0_, M1W1_, M1W2_, M2W0_, M2W1_, M2W2_, We, T0, T1, T2, P0,
                 Wt1, Wt2, Wt3, Wt4, Wt5, Wt6, Wet, Ttb, P0t};
  k_pack_small<<<624, 256, 0, stream>>>(pp);

  k_prep<<<EDGES / 4, 256, 0, stream>>>(node_f, edge_f, D1, D2, mg, Wg, latents, eoh,
                                        eidx, act, f_all, gfb, latbf, m2in);

  // MoE GEMMs; moe0 also emits scs = silu(o0[:,:64]) into m2in[:,0:64]
  k_gemm<3200, 11, 9, 160, 0, 736, false, 2>
      <<<1024, 256, 0, stream>>>(f_all, B0t, gfb, nullptr, moeout, 288, 0, m2in, nullptr, nullptr, nullptr, nullptr);
  k_gemm<2624, 9, 9, 96, 352, 736, false, 0>
      <<<1024, 256, 0, stream>>>(f_all, B1t, gfb, nullptr, moeout, 288, 160, nullptr, nullptr, nullptr, nullptr, nullptr);
  k_gemm<896, 3, 9, 32, 640, 736, false, 0>
      <<<1024, 256, 0, stream>>>(f_all, B2t, gfb, nullptr, moeout, 288, 256, nullptr, nullptr, nullptr, nullptr, nullptr);

  // lat @ We ; eoh @ T^T
  k_gemm<128, 4, 1, 128, 0, 128, false, 0>
      <<<1024, 256, 0, stream>>>(latbf, Wet, nullptr, nullptr, wbuf, 128, 0, nullptr, nullptr, nullptr, nullptr, nullptr);
  k_gemm<128, 4, 1, 128, 128, 256, false, 0>
      <<<1024, 256, 0, stream>>>(m2in, Ttb, nullptr, nullptr, tbuf, 128, 0, nullptr, nullptr, nullptr, nullptr, nullptr);

  // sps = scs @ P0 + b0  -> m1in cols 128..191 (after moe GEMMs: writes into f_all region)
  k_gemm<64, 2, 1, 64, 0, 256, true, 0>
      <<<1024, 256, 0, stream>>>(m2in, P0t, nullptr, b0, m1in, 192, 128, nullptr, nullptr, nullptr, nullptr, nullptr);

  // post: rotations/gates/P1-P2/LN; new_edge staged in d_out edge region
  k_post1<<<EDGES / 8, 256, 0, stream>>>(moeout, D1, D2, latents, act, P1, P2,
                                         wbuf, be, lng, lnb, m1in, out_edge);

  // MLP1
  k_gemm<192, 6, 1, 128, 0, 192, true, 1>
      <<<1024, 256, 0, stream>>>(m1in, Wt1, nullptr, M1b0_, h1, 128, 0, nullptr, nullptr, nullptr, nullptr, nullptr);
  k_gemm<128, 4, 1, 128, 0, 128, true, 1>
      <<<1024, 256, 0, stream>>>(h1, Wt2, nullptr, M1b1_, h2, 128, 0, nullptr, nullptr, nullptr, nullptr, nullptr);
  k_gemm<128, 4, 1, 128, 0, 128, true, 0>
      <<<1024, 256, 0, stream>>>(h2, Wt3, nullptr, M1b2_, m2in, 256, 0, nullptr, nullptr, nullptr, nullptr, nullptr);
  // MLP2; final layer fuses the latent update (EPI3) directly into out_lat
  k_gemm<256, 8, 1, 128, 0, 256, true, 1>
      <<<1024, 256, 0, stream>>>(m2in, Wt4, nullptr, M2b0_, h1, 128, 0, nullptr, nullptr, nullptr, nullptr, nullptr);
  k_gemm<128, 4, 1, 128, 0, 128, true, 1>
      <<<1024, 256, 0, stream>>>(h1, Wt5, nullptr, M2b1_, h2, 128, 0, nullptr, nullptr, nullptr, nullptr, nullptr);
  k_gemm<128, 4, 1, 128, 0, 128, true, 3>
      <<<1024, 256, 0, stream>>>(h2, Wt6, nullptr, M2b2_, nullptr, 0, 0, nullptr, out_lat, act, cutoff, latents);

  k_final<<<EDGES, 128, 0, stream>>>(tbuf, edge_f, out_edge, out_edge);
}

// Round 6
// 570.984 us; speedup vs baseline: 1.6318x; 1.0319x over previous
//
#include <hip/hip_runtime.h>
#include <hip/hip_bf16.h>
#include <stdint.h>

#define EDGES 65536

typedef unsigned int uint;
typedef unsigned short ushort;
using bf16x8 = __attribute__((ext_vector_type(8))) __bf16;
using f32x4  = __attribute__((ext_vector_type(4))) float;
using uintx4 = __attribute__((ext_vector_type(4))) uint;
using float4v = __attribute__((ext_vector_type(4))) float;

#define C_OLD 0.8944271909999159f
#define C_NEW 0.4472135954999579f
#define T_SCALE 0.08838834764831845f

__device__ __forceinline__ ushort f2bf(float f) {
  uint x = __builtin_bit_cast(uint, f);
  uint r = x + 0x7FFFu + ((x >> 16) & 1u);
  return (ushort)(r >> 16);
}
__device__ __forceinline__ float bf2f(ushort u) {
  uint x = (uint)u << 16;
  return __builtin_bit_cast(float, x);
}
__device__ __forceinline__ void gload16(const void* g, void* l) {
  __builtin_amdgcn_global_load_lds(
      (const __attribute__((address_space(1))) void*)g,
      (__attribute__((address_space(3))) void*)l, 16, 0, 0);
}

// ---------------- weight pack kernels (group-padded K windows) ----------------
// B0t: [160][3456], group k at k*384, f<336 real
__global__ __launch_bounds__(256) void k_pack_b0(const float* __restrict__ W0, ushort* __restrict__ B) {
  int idx = blockIdx.x * 256 + threadIdx.x;
  if (idx >= 160 * 3456) return;
  int o = idx / 3456, kf = idx - o * 3456;
  int k = kf / 384, f = kf - k * 384;
  float v = (f < 336) ? W0[k * 53760 + f * 160 + o] : 0.f;
  B[idx] = f2bf(v);
}
// B1t: [96][2880], group k at k*320, f<288 real (fp1 144 | fm1 144)
__global__ __launch_bounds__(256) void k_pack_b1(const float* __restrict__ Wr, const float* __restrict__ Wi, ushort* __restrict__ B) {
  int idx = blockIdx.x * 256 + threadIdx.x;
  if (idx >= 96 * 2880) return;
  int c = idx / 2880, kf = idx - c * 2880;
  int k = kf / 320, f = kf - k * 320;
  float v = 0.f;
  if (f < 288) {
    if (c < 48) v = (f < 144) ? Wr[k * 6912 + f * 48 + c] : -Wi[k * 6912 + (f - 144) * 48 + c];
    else        v = (f < 144) ? Wi[k * 6912 + f * 48 + (c - 48)] : Wr[k * 6912 + (f - 144) * 48 + (c - 48)];
  }
  B[idx] = f2bf(v);
}
// B2t: [32][1152], group k at k*128, f<96 real (fp2 48 | fm2 48)
__global__ __launch_bounds__(256) void k_pack_b2(const float* __restrict__ Wr, const float* __restrict__ Wi, ushort* __restrict__ B) {
  int idx = blockIdx.x * 256 + threadIdx.x;
  if (idx >= 32 * 1152) return;
  int c = idx / 1152, kf = idx - c * 1152;
  int k = kf / 128, f = kf - k * 128;
  float v = 0.f;
  if (f < 96) {
    if (c < 16) v = (f < 48) ? Wr[k * 768 + f * 16 + c] : -Wi[k * 768 + (f - 48) * 16 + c];
    else        v = (f < 48) ? Wi[k * 768 + f * 16 + (c - 16)] : Wr[k * 768 + (f - 48) * 16 + (c - 16)];
  }
  B[idx] = f2bf(v);
}
struct PackPtrs {
  const float *s0, *s1, *s2, *s3, *s4, *s5, *we, *t0, *t1, *t2, *p0;
  ushort *d0, *d1, *d2, *d3, *d4, *d5, *dwe, *dtt, *dp0;
};
__global__ __launch_bounds__(256) void k_pack_small(PackPtrs p) {
  int idx = blockIdx.x * 256 + threadIdx.x;
  if (idx < 24576) {
    int n = idx / 192, k = idx - n * 192;
    p.d0[idx] = f2bf(p.s0[k * 128 + n]);
  } else if (idx < 40960) {
    int q = idx - 24576; int n = q >> 7, k = q & 127;
    p.d1[q] = f2bf(p.s1[k * 128 + n]);
  } else if (idx < 57344) {
    int q = idx - 40960; int n = q >> 7, k = q & 127;
    p.d2[q] = f2bf(p.s2[k * 128 + n]);
  } else if (idx < 90112) {
    int q = idx - 57344; int n = q / 256, k = q - n * 256;
    p.d3[q] = f2bf(p.s3[k * 128 + n]);
  } else if (idx < 106496) {
    int q = idx - 90112; int n = q >> 7, k = q & 127;
    p.d4[q] = f2bf(p.s4[k * 128 + n]);
  } else if (idx < 122880) {
    int q = idx - 106496; int n = q >> 7, k = q & 127;
    p.d5[q] = f2bf(p.s5[k * 128 + n]);
  } else if (idx < 139264) {
    int q = idx - 122880; int n = q >> 7, k = q & 127;
    p.dwe[q] = f2bf((n < 112) ? p.we[k * 112 + n] : 0.f);
  } else if (idx < 155648) {
    int q = idx - 139264; int o = q >> 7, h = q & 127;
    float v = 0.f;
    if (o < 64) v = p.t0[o * 128 + h];
    else if (o < 96) v = p.t1[(o - 64) * 128 + h];
    else if (o < 112) v = p.t2[(o - 96) * 128 + h];
    p.dtt[q] = f2bf(v);
  } else if (idx < 159744) {
    int q = idx - 155648; int n = q >> 6, k = q & 63;
    p.dp0[q] = f2bf(p.p0[k * 64 + n]);
  }
}

// ---------------- prep: gather + Wigner rotate + softmax gates (wave-per-edge) ----------------
// f_all row (832 ushorts):
// [0:192 x0 scalars | 192 y1_i1 | 288 y2_i2 | 336 pad48 |
//  384 y1_i2 | 480 y2_i3 | 528 y1_i0 | 624 y2_i1 | 672 pad32 |
//  704 y2_i4 | 752 y2_i0 | 800 pad32]
__global__ __launch_bounds__(256) void k_prep(
    const float* __restrict__ node_f, const float* __restrict__ edge_f,
    const float* __restrict__ D1g, const float* __restrict__ D2g,
    const float* __restrict__ mg_g, const float* __restrict__ Wg,
    const float* __restrict__ latg, const float* __restrict__ eohg,
    const int* __restrict__ eidx, const int* __restrict__ act,
    ushort* __restrict__ f_all, float* __restrict__ gf_out,
    ushort* __restrict__ lat_bf, ushort* __restrict__ mlp2_in) {
  __shared__ float sh[4][1244];
  const int w = threadIdx.x >> 6, lane = threadIdx.x & 63;
  const int e = blockIdx.x * 4 + w;
  float* s = sh[w];
  float* s_nc = s;
  float* s_ef = s + 240;
  float* s_nn = s + 480;
  float* s_d1 = s + 720;
  float* s_d2 = s + 729;
  float* s_mg = s + 754;
  float* s_lg = s + 818;
  ushort* row = (ushort*)(s + 828);  // 832 ushorts = 416 floats
  const int ae = act[e];
  const int ec = eidx[ae], en = eidx[EDGES + ae];
  if (lane < 60) {
    ((float4v*)s_nc)[lane] = ((const float4v*)(node_f + (size_t)ec * 240))[lane];
    ((float4v*)s_ef)[lane] = ((const float4v*)(edge_f + (size_t)e * 240))[lane];
    ((float4v*)s_nn)[lane] = ((const float4v*)(node_f + (size_t)en * 240))[lane];
  }
  if (lane < 9)  s_d1[lane] = D1g[e * 9 + lane];
  if (lane < 25) s_d2[lane] = D2g[e * 25 + lane];
  s_mg[lane] = mg_g[e * 64 + lane];
  {
    const float* lp = latg + (size_t)ae * 128;
    float a0 = lp[2 * lane], a1 = lp[2 * lane + 1];
    ((uint*)lat_bf)[(size_t)e * 64 + lane] = (uint)f2bf(a0) | ((uint)f2bf(a1) << 16);
    const float* ep = eohg + (size_t)e * 128;
    a0 = ep[2 * lane]; a1 = ep[2 * lane + 1];
    ((uint*)mlp2_in)[(size_t)e * 128 + 64 + lane] = (uint)f2bf(a0) | ((uint)f2bf(a1) << 16);
  }
  if (lane < 8) {
    float a = 0.f;
    for (int h = 0; h < 64; ++h) a += s_mg[h] * Wg[h * 8 + lane];
    s_lg[lane] = a;
  }
  if (lane < 12) {
    float m = s_lg[0];
    for (int j = 1; j < 8; ++j) m = fmaxf(m, s_lg[j]);
    float den = 0.f;
    for (int j = 0; j < 8; ++j) den += __expf(s_lg[j] - m);
    float v = 0.f;
    if (lane < 8) v = __expf(s_lg[lane] - m) / den;
    else if (lane == 8) v = 1.f;
    gf_out[e * 12 + lane] = v;
  }
  row[lane]       = f2bf(s_nc[lane]);
  row[64 + lane]  = f2bf(s_ef[lane]);
  row[128 + lane] = f2bf(s_nn[lane]);
  // zero pads
  if (lane < 48) row[336 + lane] = 0;
  if (lane < 32) { row[672 + lane] = 0; row[800 + lane] = 0; }
  // y1: i=0 -> 528, i=1 -> 192, i=2 -> 384
#pragma unroll
  for (int it = 0; it < 5; ++it) {
    int q = lane + it * 64;
    if (q < 288) {
      int i = q / 96, c = q - i * 96;
      const float* src = (c < 32) ? s_nc : (c < 64) ? s_ef : s_nn;
      int base = 64 + (c & 31) * 3;
      float v = s_d1[i * 3] * src[base] + s_d1[i * 3 + 1] * src[base + 1] + s_d1[i * 3 + 2] * src[base + 2];
      int dst = (i == 0) ? 528 : (i == 1) ? 192 : 384;
      row[dst + c] = f2bf(v);
    }
  }
  // y2: i=0 -> 752, i=1 -> 624, i=2 -> 288, i=3 -> 480, i=4 -> 704
#pragma unroll
  for (int it = 0; it < 4; ++it) {
    int q = lane + it * 64;
    if (q < 240) {
      int i = q / 48, c = q - i * 48;
      const float* src = (c < 16) ? s_nc : (c < 32) ? s_ef : s_nn;
      int base = 160 + (c & 15) * 5;
      float v = s_d2[i * 5] * src[base] + s_d2[i * 5 + 1] * src[base + 1] +
                s_d2[i * 5 + 2] * src[base + 2] + s_d2[i * 5 + 3] * src[base + 3] +
                s_d2[i * 5 + 4] * src[base + 4];
      int dst = (i == 0) ? 752 : (i == 1) ? 624 : (i == 2) ? 288 : (i == 3) ? 480 : 704;
      row[dst + c] = f2bf(v);
    }
  }
  const uintx4* row4 = (const uintx4*)row;
  uintx4* dst4 = (uintx4*)(f_all + (size_t)e * 832);
#pragma unroll
  for (int it = 0; it < 2; ++it) {
    int q = lane + it * 64;
    if (q < 104) dst4[q] = row4[q];
  }
}

// ---------------- bf16 MFMA GEMM: BM=64, double-buffered DMA, uniform group windows ----
// SPG2 = 64-K steps per expert group (group K-window = SPG2*64, same A bytes for all groups).
// EPI: 0=raw bf16, 1=silu bf16, 2=raw + silu(c<64) to outb2 (stride 256), 3=lat-update f32
template <int KZP, int SPG2, int NGRP, int NCOL, int FOFF, int ASTRIDE, bool HASBIAS, int EPI>
__global__ __launch_bounds__(256) void k_gemm(
    const ushort* __restrict__ A, const ushort* __restrict__ Bt,
    const float* __restrict__ gf, const float* __restrict__ bias,
    ushort* __restrict__ outb, int ob_stride, int ob_off,
    ushort* __restrict__ outb2, float* __restrict__ outf,
    const int* __restrict__ act, const float* __restrict__ cutg,
    const float* __restrict__ latg) {
  constexpr int NFW = NCOL / 32;
  constexpr int A_BYTES = 64 * 128;
  constexpr int B_BYTES = NCOL * 128;
  constexpr int NT2 = KZP / 64;
  static_assert(NCOL % 32 == 0 && KZP % 64 == 0, "geom");
  __shared__ char sm[2 * A_BYTES + 2 * B_BYTES + ((NGRP > 1) ? 3072 + 64 : 16)];
  char* a_lds = sm;
  char* b_lds = sm + 2 * A_BYTES;
  float* gf_lds = (float*)(sm + 2 * A_BYTES + 2 * B_BYTES);
  const int tid = threadIdx.x;
  const int lane = tid & 63, w = tid >> 6;
  const int wr = w >> 1, wc = w & 1;
  const int g16 = lane >> 4;
  const int e0 = blockIdx.x * 64;
  const f32x4 vzero = {0.f, 0.f, 0.f, 0.f};

  if constexpr (NGRP > 1) {
    for (int q = tid; q < 768; q += 256)
      gf_lds[q] = gf[(size_t)(e0 + q / 12) * 12 + (q - (q / 12) * 12)];
  }

  // loop-invariant per-lane DMA source bases
  const char* aSrc[2];
#pragma unroll
  for (int it = 0; it < 2; ++it) {
    int q = (w + it * 4) * 64 + lane;
    int r = q >> 3, ch = (q & 7) ^ (r & 7);
    aSrc[it] = (const char*)(A + (size_t)(e0 + r) * ASTRIDE + FOFF) + ch * 16;
  }
  const char* bSrc[NFW > 0 ? NCOL / 32 : 1];
#pragma unroll
  for (int it = 0; it < NCOL / 32; ++it) {
    int q = (w + it * 4) * 64 + lane;
    int c = q >> 3, ch = (q & 7) ^ (c & 7);
    bSrc[it] = (const char*)(Bt + (size_t)c * KZP) + ch * 16;
  }

  auto stage = [&](int t2, int buf) {
    int aoff = (NGRP > 1) ? (t2 % SPG2) * 128 : t2 * 128;
#pragma unroll
    for (int it = 0; it < 2; ++it)
      gload16(aSrc[it] + aoff, a_lds + buf * A_BYTES + (w + it * 4) * 1024);
#pragma unroll
    for (int it = 0; it < NCOL / 32; ++it)
      gload16(bSrc[it] + t2 * 128, b_lds + buf * B_BYTES + (w + it * 4) * 1024);
  };

  f32x4 accS[2][NFW], accC[2][NFW];
#pragma unroll
  for (int mi = 0; mi < 2; ++mi)
#pragma unroll
    for (int n = 0; n < NFW; ++n) { accS[mi][n] = vzero; accC[mi][n] = vzero; }

  stage(0, 0);
  __syncthreads();
  int cur = 0;
  for (int t2 = 0; t2 < NT2; ++t2) {
    if (t2 + 1 < NT2) stage(t2 + 1, cur ^ 1);
    const char* aL = a_lds + cur * A_BYTES;
    const char* bL = b_lds + cur * B_BYTES;
#pragma unroll
    for (int s = 0; s < 2; ++s) {
      bf16x8 a[2];
#pragma unroll
      for (int mi = 0; mi < 2; ++mi) {
        int rA = wr * 32 + mi * 16 + (lane & 15);
        int slot = (s * 4 + g16) ^ (rA & 7);
        a[mi] = *(const bf16x8*)(aL + rA * 128 + slot * 16);
      }
#pragma unroll
      for (int n = 0; n < NFW; ++n) {
        int cB = (wc * NFW + n) * 16 + (lane & 15);
        int slot = (s * 4 + g16) ^ (cB & 7);
        bf16x8 b = *(const bf16x8*)(bL + cB * 128 + slot * 16);
#pragma unroll
        for (int mi = 0; mi < 2; ++mi) {
          if constexpr (NGRP > 1)
            accC[mi][n] = __builtin_amdgcn_mfma_f32_16x16x32_bf16(a[mi], b, accC[mi][n], 0, 0, 0);
          else
            accS[mi][n] = __builtin_amdgcn_mfma_f32_16x16x32_bf16(a[mi], b, accS[mi][n], 0, 0, 0);
        }
      }
    }
    if constexpr (NGRP > 1) {
      if (t2 % SPG2 == SPG2 - 1) {
        int gx = t2 / SPG2;
        float g4[2][4];
#pragma unroll
        for (int mi = 0; mi < 2; ++mi)
#pragma unroll
          for (int j = 0; j < 4; ++j)
            g4[mi][j] = gf_lds[(wr * 32 + mi * 16 + g16 * 4 + j) * 12 + gx];
#pragma unroll
        for (int mi = 0; mi < 2; ++mi)
#pragma unroll
          for (int n = 0; n < NFW; ++n) {
#pragma unroll
            for (int j = 0; j < 4; ++j) accS[mi][n][j] += g4[mi][j] * accC[mi][n][j];
            accC[mi][n] = vzero;
          }
      }
    }
    __syncthreads();
    cur ^= 1;
  }

#pragma unroll
  for (int mi = 0; mi < 2; ++mi) {
    const int row0 = wr * 32 + mi * 16 + g16 * 4;
#pragma unroll
    for (int n = 0; n < NFW; ++n) {
      const int c = (wc * NFW + n) * 16 + (lane & 15);
      float bv = 0.f;
      if constexpr (HASBIAS) bv = bias[c];
#pragma unroll
      for (int j = 0; j < 4; ++j) {
        float v = accS[mi][n][j] + bv;
        const int er = e0 + row0 + j;
        if constexpr (EPI == 1) v = v / (1.f + __expf(-v));
        if constexpr (EPI == 3) {
          int ae = act[er];
          outf[(size_t)ae * 128 + c] = C_NEW * cutg[ae] * v + C_OLD * latg[(size_t)ae * 128 + c];
        } else {
          outb[(size_t)er * ob_stride + ob_off + c] = f2bf(v);
          if constexpr (EPI == 2) {
            if ((wc * NFW + n) * 16 < 64)
              outb2[(size_t)er * 256 + c] = f2bf(v / (1.f + __expf(-v)));
          }
        }
      }
    }
  }
}

// ---------------- post-MoE: 8 edges/block, LDS-staged P1/P2 ----------------
__global__ __launch_bounds__(256) void k_post1(
    const ushort* __restrict__ moeout,
    const float* __restrict__ D1g, const float* __restrict__ D2g,
    const float* __restrict__ latg, const int* __restrict__ act,
    const float* __restrict__ P1, const float* __restrict__ P2,
    const ushort* __restrict__ wbuf, const float* __restrict__ beg,
    const float* __restrict__ lng, const float* __restrict__ lnb,
    ushort* __restrict__ m1in, float* __restrict__ new_edge) {
  __shared__ float SM[7488];
  float* sP1 = SM;
  float* sP2 = SM + 1024;
  float* be_s = SM + 1280;
  float* lng_s = SM + 1392;
  float* lnb_s = SM + 1520;
  float* sO   = SM + 1648;
  float* sLat = SM + 3440;
  float* sWv  = SM + 4464;
  float* sU1  = SM + 5360;
  float* sU2  = SM + 6128;
  float* sSg  = SM + 6768;
  float* sD1  = SM + 7152;
  float* sD2  = SM + 7248;
  float* sMu  = SM + 7472;
  float* sRs  = SM + 7480;
  const int t = threadIdx.x;
  const int e8 = blockIdx.x * 8;

  for (int q = t; q < 368; q += 256) {
    if (q < 112) be_s[q] = beg[q];
    else if (q < 240) lng_s[q - 112] = lng[q - 112];
    else lnb_s[q - 240] = lnb[q - 240];
  }
  for (int q = t; q < 1024; q += 256) {
    int d = q >> 5, c = q & 31;
    sP1[d * 32 + ((((c >> 2) + d) & 7) << 2) + (c & 3)] = P1[c * 32 + d];
  }
  {
    int d = t >> 4, c = t & 15;
    if (t < 256) sP2[d * 16 + ((((c >> 2) + d) & 3) << 2) + (c & 3)] = P2[c * 16 + d];
  }
  {
    int e = t >> 5, kq = t & 31;
    if (kq < 28) {
      uintx4 raw = *(const uintx4*)(moeout + (size_t)(e8 + e) * 288 + 64 + kq * 8);
      float* d = sO + e * 224 + kq * 8;
#pragma unroll
      for (int j = 0; j < 4; ++j) {
        uint u = raw[j];
        d[2 * j] = bf2f((ushort)(u & 0xFFFF));
        d[2 * j + 1] = bf2f((ushort)(u >> 16));
      }
    }
  }
  {
    int e = t >> 5, i = t & 31;
    int ae = act[e8 + e];
    ((float4v*)(sLat + e * 128))[i] = ((const float4v*)(latg + (size_t)ae * 128))[i];
  }
  {
    int e = t >> 4, kq = t & 15;
    if (e < 8 && kq < 14) {
      uintx4 raw = *(const uintx4*)(wbuf + (size_t)(e8 + e) * 128 + kq * 8);
      float* d = sWv + e * 112 + kq * 8;
#pragma unroll
      for (int j = 0; j < 4; ++j) {
        uint u = raw[j];
        d[2 * j] = bf2f((ushort)(u & 0xFFFF));
        d[2 * j + 1] = bf2f((ushort)(u >> 16));
      }
    }
  }
  for (int q = t; q < 512; q += 256) {
    int e = q >> 6, i = q & 63;
    if (i < 9) sD1[e * 12 + i] = D1g[(size_t)(e8 + e) * 9 + i];
    else if (i < 34) sD2[e * 28 + (i - 9)] = D2g[(size_t)(e8 + e) * 25 + (i - 9)];
  }
  __syncthreads();

  for (int q = t; q < 384; q += 256) {
    int e = q / 48, c = q - (q / 48) * 48;
    sSg[e * 48 + c] = 1.f / (1.f + __expf(-sO[e * 224 + c]));
  }
  __syncthreads();

  for (int q = t; q < 768; q += 256) {
    int e = q / 96, r = q - (q / 96) * 96;
    int m = r >> 5, c = r & 31;
    const float* o = sO + e * 224;
    const float* d1 = sD1 + e * 12;
    float v = d1[m] * o[144 + c] + d1[3 + m] * o[48 + c] + d1[6 + m] * o[96 + c];
    sU1[e * 96 + m * 32 + c] = v * sSg[e * 48 + c];
  }
  for (int q = t; q < 640; q += 256) {
    int e = q / 80, r = q - (q / 80) * 80;
    int m = r >> 4, c = r & 15;
    const float* o = sO + e * 224;
    const float* d2 = sD2 + e * 28;
    float v = d2[m] * o[208 + c] + d2[5 + m] * o[176 + c] + d2[10 + m] * o[80 + c] +
              d2[15 + m] * o[128 + c] + d2[20 + m] * o[192 + c];
    sU2[e * 80 + m * 16 + c] = v * sSg[e * 48 + 32 + c];
  }
  {
    int eg = t >> 5, l = t & 31;
    const float* lt = sLat + eg * 128;
    float v0 = lt[l], v1 = lt[l + 32], v2 = lt[l + 64], v3 = lt[l + 96];
    float sum = v0 + v1 + v2 + v3;
    float sq = v0 * v0 + v1 * v1 + v2 * v2 + v3 * v3;
#pragma unroll
    for (int m = 16; m > 0; m >>= 1) {
      sum += __shfl_xor(sum, m);
      sq += __shfl_xor(sq, m);
    }
    if (l == 0) {
      float mu = sum * (1.f / 128.f);
      float var = sq * (1.f / 128.f) - mu * mu;
      sMu[eg] = mu;
      sRs[eg] = rsqrtf(var + 1e-5f);
    }
  }
  __syncthreads();

  for (int q = t; q < 768; q += 256) {
    int e = q / 96, r = q - (q / 96) * 96;
    int m = r >> 5, d = r & 31;
    const float* u = sU1 + e * 96 + m * 32;
    float acc = 0.f;
#pragma unroll
    for (int cq = 0; cq < 8; ++cq) {
      float4v p = *(const float4v*)(sP1 + d * 32 + (((cq + d) & 7) << 2));
      float4v uu = *(const float4v*)(u + cq * 4);
      acc += p[0] * uu[0] + p[1] * uu[1] + p[2] * uu[2] + p[3] * uu[3];
    }
    new_edge[(size_t)(e8 + e) * 240 + 64 + d * 3 + m] = acc * (sWv[e * 112 + 64 + d] + be_s[64 + d]);
  }
  for (int q = t; q < 640; q += 256) {
    int e = q / 80, r = q - (q / 80) * 80;
    int m = r >> 4, d = r & 15;
    const float* u = sU2 + e * 80 + m * 16;
    float acc = 0.f;
#pragma unroll
    for (int cq = 0; cq < 4; ++cq) {
      float4v p = *(const float4v*)(sP2 + d * 16 + (((cq + d) & 3) << 2));
      float4v uu = *(const float4v*)(u + cq * 4);
      acc += p[0] * uu[0] + p[1] * uu[1] + p[2] * uu[2] + p[3] * uu[3];
    }
    new_edge[(size_t)(e8 + e) * 240 + 160 + d * 5 + m] = acc * (sWv[e * 112 + 96 + d] + be_s[96 + d]);
  }
  for (int q = t; q < 512; q += 256) {
    int e = q >> 6, d = q & 63;
    float sp = bf2f(m1in[(size_t)(e8 + e) * 192 + 128 + d]);
    new_edge[(size_t)(e8 + e) * 240 + d] = sp * (sWv[e * 112 + d] + be_s[d]);
  }
  for (int q = t; q < 512; q += 256) {
    int e = q >> 6, i2 = q & 63;
    const float* lt = sLat + e * 128;
    float mu = sMu[e], rs = sRs[e];
    int i = 2 * i2;
    float l0 = (lt[i] - mu) * rs * lng_s[i] + lnb_s[i];
    float l1 = (lt[i + 1] - mu) * rs * lng_s[i + 1] + lnb_s[i + 1];
    ((uint*)m1in)[(size_t)(e8 + e) * 96 + i2] = (uint)f2bf(l0) | ((uint)f2bf(l1) << 16);
  }
}

// ---------------- final combine (edge part only) ----------------
__global__ __launch_bounds__(128) void k_final(
    const ushort* __restrict__ tbuf,
    const float* __restrict__ efg, const float* __restrict__ new_edge,
    float* __restrict__ out_edge) {
  __shared__ float tv[112];
  const int t = threadIdx.x;
  const int e = blockIdx.x;
  if (t < 112) tv[t] = bf2f(tbuf[e * 128 + t]) * T_SCALE;
  __syncthreads();
  for (int d = t; d < 240; d += 128) {
    float v = C_OLD * efg[(size_t)e * 240 + d] + C_NEW * new_edge[(size_t)e * 240 + d];
    float f;
    if (d < 64) f = tv[d];
    else if (d < 160) f = tv[64 + (d - 64) / 3];
    else f = tv[96 + (d - 160) / 5];
    out_edge[(size_t)e * 240 + d] = v * (1.f + f);
  }
}

extern "C" void kernel_launch(void* const* d_in, const int* in_sizes, int n_in,
                              void* d_out, int out_size, void* d_ws, size_t ws_size,
                              hipStream_t stream) {
  const float* latents = (const float*)d_in[0];
  const float* node_f  = (const float*)d_in[1];
  const float* edge_f  = (const float*)d_in[3];
  const float* cutoff  = (const float*)d_in[5];
  const float* eoh     = (const float*)d_in[6];
  const float* D1      = (const float*)d_in[7];
  const float* D2      = (const float*)d_in[8];
  const float* mg      = (const float*)d_in[9];
  const int*   eidx    = (const int*)d_in[10];
  const int*   act     = (const int*)d_in[11];
  const float* Wg      = (const float*)d_in[12];
  const float* W0      = (const float*)d_in[13];
  const float* W1r     = (const float*)d_in[14];
  const float* W1i     = (const float*)d_in[15];
  const float* W2r     = (const float*)d_in[16];
  const float* W2i     = (const float*)d_in[17];
  const float* P0      = (const float*)d_in[18];
  const float* b0      = (const float*)d_in[19];
  const float* P1      = (const float*)d_in[20];
  const float* P2      = (const float*)d_in[21];
  const float* We      = (const float*)d_in[22];
  const float* be      = (const float*)d_in[23];
  const float* lng     = (const float*)d_in[24];
  const float* lnb     = (const float*)d_in[25];
  const float* M1W0_   = (const float*)d_in[26];
  const float* M1b0_   = (const float*)d_in[27];
  const float* M1W1_   = (const float*)d_in[28];
  const float* M1b1_   = (const float*)d_in[29];
  const float* M1W2_   = (const float*)d_in[30];
  const float* M1b2_   = (const float*)d_in[31];
  const float* M2W0_   = (const float*)d_in[32];
  const float* M2b0_   = (const float*)d_in[33];
  const float* M2W1_   = (const float*)d_in[34];
  const float* M2b1_   = (const float*)d_in[35];
  const float* M2W2_   = (const float*)d_in[36];
  const float* M2b2_   = (const float*)d_in[37];
  const float* T0      = (const float*)d_in[38];
  const float* T1      = (const float*)d_in[39];
  const float* T2      = (const float*)d_in[40];

  float* out_edge = (float*)d_out;
  float* out_lat  = out_edge + (size_t)EDGES * 240;
  float* out_d1   = out_lat + (size_t)EDGES * 128;
  float* out_d2   = out_d1 + (size_t)EDGES * 9;

  char* ws = (char*)d_ws;
  size_t off = 0;
  auto alloc = [&](size_t bytes) -> char* {
    char* p = ws + off;
    off += (bytes + 255) & ~size_t(255);
    return p;
  };
  ushort* f_all  = (ushort*)alloc((size_t)EDGES * 832 * 2);
  float*  gfb    = (float*) alloc((size_t)EDGES * 12 * 4);
  ushort* moeout = (ushort*)alloc((size_t)EDGES * 288 * 2);
  ushort* m2in   = (ushort*)alloc((size_t)EDGES * 256 * 2);
  ushort* latbf  = (ushort*)alloc((size_t)EDGES * 128 * 2);
  ushort* wbuf   = (ushort*)alloc((size_t)EDGES * 128 * 2);
  ushort* B0t    = (ushort*)alloc(160 * 3456 * 2);
  ushort* B1t    = (ushort*)alloc(96 * 2880 * 2);
  ushort* B2t    = (ushort*)alloc(32 * 1152 * 2);
  ushort* Wt1    = (ushort*)alloc(128 * 192 * 2);
  ushort* Wt2    = (ushort*)alloc(128 * 128 * 2);
  ushort* Wt3    = (ushort*)alloc(128 * 128 * 2);
  ushort* Wt4    = (ushort*)alloc(128 * 256 * 2);
  ushort* Wt5    = (ushort*)alloc(128 * 128 * 2);
  ushort* Wt6    = (ushort*)alloc(128 * 128 * 2);
  ushort* Wet    = (ushort*)alloc(128 * 128 * 2);
  ushort* Ttb    = (ushort*)alloc(128 * 128 * 2);
  ushort* P0t    = (ushort*)alloc(64 * 64 * 2);

  ushort* m1in = f_all;
  ushort* h1   = f_all + (size_t)EDGES * 192;
  ushort* h2   = f_all + (size_t)EDGES * 320;
  ushort* tbuf = latbf;

  hipMemcpyAsync(out_lat, (const void*)latents, (size_t)EDGES * 128 * 4, hipMemcpyDeviceToDevice, stream);
  hipMemcpyAsync(out_d1, (const void*)D1, (size_t)EDGES * 9 * 4, hipMemcpyDeviceToDevice, stream);
  hipMemcpyAsync(out_d2, (const void*)D2, (size_t)EDGES * 25 * 4, hipMemcpyDeviceToDevice, stream);

  if (ws_size < off) return;

  k_pack_b0<<<2160, 256, 0, stream>>>(W0, B0t);
  k_pack_b1<<<1080, 256, 0, stream>>>(W1r, W1i, B1t);
  k_pack_b2<<<144, 256, 0, stream>>>(W2r, W2i, B2t);
  PackPtrs pp = {M1W0_, M1W1_, M1W2_, M2W0_, M2W1_, M2W2_, We, T0, T1, T2, P0,
                 Wt1, Wt2, Wt3, Wt4, Wt5, Wt6, Wet, Ttb, P0t};
  k_pack_small<<<624, 256, 0, stream>>>(pp);

  k_prep<<<EDGES / 4, 256, 0, stream>>>(node_f, edge_f, D1, D2, mg, Wg, latents, eoh,
                                        eidx, act, f_all, gfb, latbf, m2in);

  // MoE GEMMs; moe0 also emits scs = silu(o0[:,:64]) into m2in[:,0:64]
  k_gemm<3456, 6, 9, 160, 0, 832, false, 2>
      <<<1024, 256, 0, stream>>>(f_all, B0t, gfb, nullptr, moeout, 288, 0, m2in, nullptr, nullptr, nullptr, nullptr);
  k_gemm<2880, 5, 9, 96, 384, 832, false, 0>
      <<<1024, 256, 0, stream>>>(f_all, B1t, gfb, nullptr, moeout, 288, 160, nullptr, nullptr, nullptr, nullptr, nullptr);
  k_gemm<1152, 2, 9, 32, 704, 832, false, 0>
      <<<1024, 256, 0, stream>>>(f_all, B2t, gfb, nullptr, moeout, 288, 256, nullptr, nullptr, nullptr, nullptr, nullptr);

  // lat @ We ; eoh @ T^T
  k_gemm<128, 1, 1, 128, 0, 128, false, 0>
      <<<1024, 256, 0, stream>>>(latbf, Wet, nullptr, nullptr, wbuf, 128, 0, nullptr, nullptr, nullptr, nullptr, nullptr);
  k_gemm<128, 1, 1, 128, 128, 256, false, 0>
      <<<1024, 256, 0, stream>>>(m2in, Ttb, nullptr, nullptr, tbuf, 128, 0, nullptr, nullptr, nullptr, nullptr, nullptr);

  // sps = scs @ P0 + b0 -> m1in cols 128..191
  k_gemm<64, 1, 1, 64, 0, 256, true, 0>
      <<<1024, 256, 0, stream>>>(m2in, P0t, nullptr, b0, m1in, 192, 128, nullptr, nullptr, nullptr, nullptr, nullptr);

  k_post1<<<EDGES / 8, 256, 0, stream>>>(moeout, D1, D2, latents, act, P1, P2,
                                         wbuf, be, lng, lnb, m1in, out_edge);

  // MLP1
  k_gemm<192, 1, 1, 128, 0, 192, true, 1>
      <<<1024, 256, 0, stream>>>(m1in, Wt1, nullptr, M1b0_, h1, 128, 0, nullptr, nullptr, nullptr, nullptr, nullptr);
  k_gemm<128, 1, 1, 128, 0, 128, true, 1>
      <<<1024, 256, 0, stream>>>(h1, Wt2, nullptr, M1b1_, h2, 128, 0, nullptr, nullptr, nullptr, nullptr, nullptr);
  k_gemm<128, 1, 1, 128, 0, 128, true, 0>
      <<<1024, 256, 0, stream>>>(h2, Wt3, nullptr, M1b2_, m2in, 256, 0, nullptr, nullptr, nullptr, nullptr, nullptr);
  // MLP2; final layer fuses the latent update (EPI3)
  k_gemm<256, 1, 1, 128, 0, 256, true, 1>
      <<<1024, 256, 0, stream>>>(m2in, Wt4, nullptr, M2b0_, h1, 128, 0, nullptr, nullptr, nullptr, nullptr, nullptr);
  k_gemm<128, 1, 1, 128, 0, 128, true, 1>
      <<<1024, 256, 0, stream>>>(h1, Wt5, nullptr, M2b1_, h2, 128, 0, nullptr, nullptr, nullptr, nullptr, nullptr);
  k_gemm<128, 1, 1, 128, 0, 128, true, 3>
      <<<1024, 256, 0, stream>>>(h2, Wt6, nullptr, M2b2_, nullptr, 0, 0, nullptr, out_lat, act, cutoff, latents);

  k_final<<<EDGES, 128, 0, stream>>>(tbuf, edge_f, out_edge, out_edge);
}

// Round 7
// 548.273 us; speedup vs baseline: 1.6994x; 1.0414x over previous
//
#include <hip/hip_runtime.h>
#include <hip/hip_bf16.h>
#include <stdint.h>

#define EDGES 65536

typedef unsigned int uint;
typedef unsigned short ushort;
using bf16x8 = __attribute__((ext_vector_type(8))) __bf16;
using f32x4  = __attribute__((ext_vector_type(4))) float;
using uintx4 = __attribute__((ext_vector_type(4))) uint;
using float4v = __attribute__((ext_vector_type(4))) float;

#define C_OLD 0.8944271909999159f
#define C_NEW 0.4472135954999579f
#define T_SCALE 0.08838834764831845f

__device__ __forceinline__ ushort f2bf(float f) {
  uint x = __builtin_bit_cast(uint, f);
  uint r = x + 0x7FFFu + ((x >> 16) & 1u);
  return (ushort)(r >> 16);
}
__device__ __forceinline__ float bf2f(ushort u) {
  uint x = (uint)u << 16;
  return __builtin_bit_cast(float, x);
}
__device__ __forceinline__ void gload16(const void* g, void* l) {
  __builtin_amdgcn_global_load_lds(
      (const __attribute__((address_space(1))) void*)g,
      (__attribute__((address_space(3))) void*)l, 16, 0, 0);
}

// ---------------- weight pack kernels (group-padded K windows) ----------------
__global__ __launch_bounds__(256) void k_pack_b0(const float* __restrict__ W0, ushort* __restrict__ B) {
  int idx = blockIdx.x * 256 + threadIdx.x;
  if (idx >= 160 * 3456) return;
  int o = idx / 3456, kf = idx - o * 3456;
  int k = kf / 384, f = kf - k * 384;
  float v = (f < 336) ? W0[k * 53760 + f * 160 + o] : 0.f;
  B[idx] = f2bf(v);
}
__global__ __launch_bounds__(256) void k_pack_b1(const float* __restrict__ Wr, const float* __restrict__ Wi, ushort* __restrict__ B) {
  int idx = blockIdx.x * 256 + threadIdx.x;
  if (idx >= 96 * 2880) return;
  int c = idx / 2880, kf = idx - c * 2880;
  int k = kf / 320, f = kf - k * 320;
  float v = 0.f;
  if (f < 288) {
    if (c < 48) v = (f < 144) ? Wr[k * 6912 + f * 48 + c] : -Wi[k * 6912 + (f - 144) * 48 + c];
    else        v = (f < 144) ? Wi[k * 6912 + f * 48 + (c - 48)] : Wr[k * 6912 + (f - 144) * 48 + (c - 48)];
  }
  B[idx] = f2bf(v);
}
__global__ __launch_bounds__(256) void k_pack_b2(const float* __restrict__ Wr, const float* __restrict__ Wi, ushort* __restrict__ B) {
  int idx = blockIdx.x * 256 + threadIdx.x;
  if (idx >= 32 * 1152) return;
  int c = idx / 1152, kf = idx - c * 1152;
  int k = kf / 128, f = kf - k * 128;
  float v = 0.f;
  if (f < 96) {
    if (c < 16) v = (f < 48) ? Wr[k * 768 + f * 16 + c] : -Wi[k * 768 + (f - 48) * 16 + c];
    else        v = (f < 48) ? Wi[k * 768 + f * 16 + (c - 16)] : Wr[k * 768 + (f - 48) * 16 + (c - 16)];
  }
  B[idx] = f2bf(v);
}
struct PackPtrs {
  const float *s0, *s1, *s2, *s3, *s4, *s5, *we, *t0, *t1, *t2, *p0;
  ushort *d0, *d1, *d2, *d3, *d4, *d5, *dwe, *dtt, *dp0;
};
__global__ __launch_bounds__(256) void k_pack_small(PackPtrs p) {
  int idx = blockIdx.x * 256 + threadIdx.x;
  if (idx < 24576) {
    int n = idx / 192, k = idx - n * 192;
    p.d0[idx] = f2bf(p.s0[k * 128 + n]);
  } else if (idx < 40960) {
    int q = idx - 24576; int n = q >> 7, k = q & 127;
    p.d1[q] = f2bf(p.s1[k * 128 + n]);
  } else if (idx < 57344) {
    int q = idx - 40960; int n = q >> 7, k = q & 127;
    p.d2[q] = f2bf(p.s2[k * 128 + n]);
  } else if (idx < 90112) {
    int q = idx - 57344; int n = q / 256, k = q - n * 256;
    p.d3[q] = f2bf(p.s3[k * 128 + n]);
  } else if (idx < 106496) {
    int q = idx - 90112; int n = q >> 7, k = q & 127;
    p.d4[q] = f2bf(p.s4[k * 128 + n]);
  } else if (idx < 122880) {
    int q = idx - 106496; int n = q >> 7, k = q & 127;
    p.d5[q] = f2bf(p.s5[k * 128 + n]);
  } else if (idx < 139264) {
    int q = idx - 122880; int n = q >> 7, k = q & 127;
    p.dwe[q] = f2bf((n < 112) ? p.we[k * 112 + n] : 0.f);
  } else if (idx < 155648) {
    int q = idx - 139264; int o = q >> 7, h = q & 127;
    float v = 0.f;
    if (o < 64) v = p.t0[o * 128 + h];
    else if (o < 96) v = p.t1[(o - 64) * 128 + h];
    else if (o < 112) v = p.t2[(o - 96) * 128 + h];
    p.dtt[q] = f2bf(v);
  } else if (idx < 159744) {
    int q = idx - 155648; int n = q >> 6, k = q & 63;
    p.dp0[q] = f2bf(p.p0[k * 64 + n]);
  }
}

// ---------------- prep: gather + Wigner rotate + softmax gates (wave-per-edge) ----------------
__global__ __launch_bounds__(256) void k_prep(
    const float* __restrict__ node_f, const float* __restrict__ edge_f,
    const float* __restrict__ D1g, const float* __restrict__ D2g,
    const float* __restrict__ mg_g, const float* __restrict__ Wg,
    const float* __restrict__ latg, const float* __restrict__ eohg,
    const int* __restrict__ eidx, const int* __restrict__ act,
    ushort* __restrict__ f_all, float* __restrict__ gf_out,
    ushort* __restrict__ lat_bf, ushort* __restrict__ mlp2_in) {
  __shared__ float sh[4][1244];
  const int w = threadIdx.x >> 6, lane = threadIdx.x & 63;
  const int e = blockIdx.x * 4 + w;
  float* s = sh[w];
  float* s_nc = s;
  float* s_ef = s + 240;
  float* s_nn = s + 480;
  float* s_d1 = s + 720;
  float* s_d2 = s + 729;
  float* s_mg = s + 754;
  float* s_lg = s + 818;
  ushort* row = (ushort*)(s + 828);
  const int ae = act[e];
  const int ec = eidx[ae], en = eidx[EDGES + ae];
  if (lane < 60) {
    ((float4v*)s_nc)[lane] = ((const float4v*)(node_f + (size_t)ec * 240))[lane];
    ((float4v*)s_ef)[lane] = ((const float4v*)(edge_f + (size_t)e * 240))[lane];
    ((float4v*)s_nn)[lane] = ((const float4v*)(node_f + (size_t)en * 240))[lane];
  }
  if (lane < 9)  s_d1[lane] = D1g[e * 9 + lane];
  if (lane < 25) s_d2[lane] = D2g[e * 25 + lane];
  s_mg[lane] = mg_g[e * 64 + lane];
  {
    const float* lp = latg + (size_t)ae * 128;
    float a0 = lp[2 * lane], a1 = lp[2 * lane + 1];
    ((uint*)lat_bf)[(size_t)e * 64 + lane] = (uint)f2bf(a0) | ((uint)f2bf(a1) << 16);
    const float* ep = eohg + (size_t)e * 128;
    a0 = ep[2 * lane]; a1 = ep[2 * lane + 1];
    ((uint*)mlp2_in)[(size_t)e * 128 + 64 + lane] = (uint)f2bf(a0) | ((uint)f2bf(a1) << 16);
  }
  if (lane < 8) {
    float a = 0.f;
    for (int h = 0; h < 64; ++h) a += s_mg[h] * Wg[h * 8 + lane];
    s_lg[lane] = a;
  }
  if (lane < 12) {
    float m = s_lg[0];
    for (int j = 1; j < 8; ++j) m = fmaxf(m, s_lg[j]);
    float den = 0.f;
    for (int j = 0; j < 8; ++j) den += __expf(s_lg[j] - m);
    float v = 0.f;
    if (lane < 8) v = __expf(s_lg[lane] - m) / den;
    else if (lane == 8) v = 1.f;
    gf_out[e * 12 + lane] = v;
  }
  row[lane]       = f2bf(s_nc[lane]);
  row[64 + lane]  = f2bf(s_ef[lane]);
  row[128 + lane] = f2bf(s_nn[lane]);
  if (lane < 48) row[336 + lane] = 0;
  if (lane < 32) { row[672 + lane] = 0; row[800 + lane] = 0; }
#pragma unroll
  for (int it = 0; it < 5; ++it) {
    int q = lane + it * 64;
    if (q < 288) {
      int i = q / 96, c = q - i * 96;
      const float* src = (c < 32) ? s_nc : (c < 64) ? s_ef : s_nn;
      int base = 64 + (c & 31) * 3;
      float v = s_d1[i * 3] * src[base] + s_d1[i * 3 + 1] * src[base + 1] + s_d1[i * 3 + 2] * src[base + 2];
      int dst = (i == 0) ? 528 : (i == 1) ? 192 : 384;
      row[dst + c] = f2bf(v);
    }
  }
#pragma unroll
  for (int it = 0; it < 4; ++it) {
    int q = lane + it * 64;
    if (q < 240) {
      int i = q / 48, c = q - i * 48;
      const float* src = (c < 16) ? s_nc : (c < 32) ? s_ef : s_nn;
      int base = 160 + (c & 15) * 5;
      float v = s_d2[i * 5] * src[base] + s_d2[i * 5 + 1] * src[base + 1] +
                s_d2[i * 5 + 2] * src[base + 2] + s_d2[i * 5 + 3] * src[base + 3] +
                s_d2[i * 5 + 4] * src[base + 4];
      int dst = (i == 0) ? 752 : (i == 1) ? 624 : (i == 2) ? 288 : (i == 3) ? 480 : 704;
      row[dst + c] = f2bf(v);
    }
  }
  const uintx4* row4 = (const uintx4*)row;
  uintx4* dst4 = (uintx4*)(f_all + (size_t)e * 832);
#pragma unroll
  for (int it = 0; it < 2; ++it) {
    int q = lane + it * 64;
    if (q < 104) dst4[q] = row4[q];
  }
}

// ---------------- bf16 MFMA GEMM: BM=64, double-buffered DMA, uniform group windows ----
// EPI: 0=raw bf16, 1=silu bf16, 2=raw + silu(c<64) to outb2 (stride 256)
template <int KZP, int SPG2, int NGRP, int NCOL, int FOFF, int ASTRIDE, bool HASBIAS, int EPI>
__global__ __launch_bounds__(256) void k_gemm(
    const ushort* __restrict__ A, const ushort* __restrict__ Bt,
    const float* __restrict__ gf, const float* __restrict__ bias,
    ushort* __restrict__ outb, int ob_stride, int ob_off,
    ushort* __restrict__ outb2) {
  constexpr int NFW = NCOL / 32;
  constexpr int A_BYTES = 64 * 128;
  constexpr int B_BYTES = NCOL * 128;
  constexpr int NT2 = KZP / 64;
  static_assert(NCOL % 32 == 0 && KZP % 64 == 0, "geom");
  __shared__ char sm[2 * A_BYTES + 2 * B_BYTES + ((NGRP > 1) ? 3072 + 64 : 16)];
  char* a_lds = sm;
  char* b_lds = sm + 2 * A_BYTES;
  float* gf_lds = (float*)(sm + 2 * A_BYTES + 2 * B_BYTES);
  const int tid = threadIdx.x;
  const int lane = tid & 63, w = tid >> 6;
  const int wr = w >> 1, wc = w & 1;
  const int g16 = lane >> 4;
  const int e0 = blockIdx.x * 64;
  const f32x4 vzero = {0.f, 0.f, 0.f, 0.f};

  if constexpr (NGRP > 1) {
    for (int q = tid; q < 768; q += 256)
      gf_lds[q] = gf[(size_t)(e0 + q / 12) * 12 + (q - (q / 12) * 12)];
  }

  const char* aSrc[2];
#pragma unroll
  for (int it = 0; it < 2; ++it) {
    int q = (w + it * 4) * 64 + lane;
    int r = q >> 3, ch = (q & 7) ^ (r & 7);
    aSrc[it] = (const char*)(A + (size_t)(e0 + r) * ASTRIDE + FOFF) + ch * 16;
  }
  const char* bSrc[NFW > 0 ? NCOL / 32 : 1];
#pragma unroll
  for (int it = 0; it < NCOL / 32; ++it) {
    int q = (w + it * 4) * 64 + lane;
    int c = q >> 3, ch = (q & 7) ^ (c & 7);
    bSrc[it] = (const char*)(Bt + (size_t)c * KZP) + ch * 16;
  }

  auto stage = [&](int t2, int buf) {
    int aoff = (NGRP > 1) ? (t2 % SPG2) * 128 : t2 * 128;
#pragma unroll
    for (int it = 0; it < 2; ++it)
      gload16(aSrc[it] + aoff, a_lds + buf * A_BYTES + (w + it * 4) * 1024);
#pragma unroll
    for (int it = 0; it < NCOL / 32; ++it)
      gload16(bSrc[it] + t2 * 128, b_lds + buf * B_BYTES + (w + it * 4) * 1024);
  };

  f32x4 accS[2][NFW], accC[2][NFW];
#pragma unroll
  for (int mi = 0; mi < 2; ++mi)
#pragma unroll
    for (int n = 0; n < NFW; ++n) { accS[mi][n] = vzero; accC[mi][n] = vzero; }

  stage(0, 0);
  __syncthreads();
  int cur = 0;
  for (int t2 = 0; t2 < NT2; ++t2) {
    if (t2 + 1 < NT2) stage(t2 + 1, cur ^ 1);
    const char* aL = a_lds + cur * A_BYTES;
    const char* bL = b_lds + cur * B_BYTES;
#pragma unroll
    for (int s = 0; s < 2; ++s) {
      bf16x8 a[2];
#pragma unroll
      for (int mi = 0; mi < 2; ++mi) {
        int rA = wr * 32 + mi * 16 + (lane & 15);
        int slot = (s * 4 + g16) ^ (rA & 7);
        a[mi] = *(const bf16x8*)(aL + rA * 128 + slot * 16);
      }
#pragma unroll
      for (int n = 0; n < NFW; ++n) {
        int cB = (wc * NFW + n) * 16 + (lane & 15);
        int slot = (s * 4 + g16) ^ (cB & 7);
        bf16x8 b = *(const bf16x8*)(bL + cB * 128 + slot * 16);
#pragma unroll
        for (int mi = 0; mi < 2; ++mi) {
          if constexpr (NGRP > 1)
            accC[mi][n] = __builtin_amdgcn_mfma_f32_16x16x32_bf16(a[mi], b, accC[mi][n], 0, 0, 0);
          else
            accS[mi][n] = __builtin_amdgcn_mfma_f32_16x16x32_bf16(a[mi], b, accS[mi][n], 0, 0, 0);
        }
      }
    }
    if constexpr (NGRP > 1) {
      if (t2 % SPG2 == SPG2 - 1) {
        int gx = t2 / SPG2;
        float g4[2][4];
#pragma unroll
        for (int mi = 0; mi < 2; ++mi)
#pragma unroll
          for (int j = 0; j < 4; ++j)
            g4[mi][j] = gf_lds[(wr * 32 + mi * 16 + g16 * 4 + j) * 12 + gx];
#pragma unroll
        for (int mi = 0; mi < 2; ++mi)
#pragma unroll
          for (int n = 0; n < NFW; ++n) {
#pragma unroll
            for (int j = 0; j < 4; ++j) accS[mi][n][j] += g4[mi][j] * accC[mi][n][j];
            accC[mi][n] = vzero;
          }
      }
    }
    __syncthreads();
    cur ^= 1;
  }

#pragma unroll
  for (int mi = 0; mi < 2; ++mi) {
    const int row0 = wr * 32 + mi * 16 + g16 * 4;
#pragma unroll
    for (int n = 0; n < NFW; ++n) {
      const int c = (wc * NFW + n) * 16 + (lane & 15);
      float bv = 0.f;
      if constexpr (HASBIAS) bv = bias[c];
#pragma unroll
      for (int j = 0; j < 4; ++j) {
        float v = accS[mi][n][j] + bv;
        const int er = e0 + row0 + j;
        if constexpr (EPI == 1) v = v / (1.f + __expf(-v));
        outb[(size_t)er * ob_stride + ob_off + c] = f2bf(v);
        if constexpr (EPI == 2) {
          if ((wc * NFW + n) * 16 < 64)
            outb2[(size_t)er * 256 + c] = f2bf(v / (1.f + __expf(-v)));
        }
      }
    }
  }
}

// ---------------- fused 6-layer MLP: 32 edges/block, X in LDS, W double-buffered ----------
struct MlpArgs {
  const ushort *m1in, *m2in, *Wt1, *Wt2, *Wt3, *Wt4, *Wt5, *Wt6;
  const float *b1, *b2, *b3, *b4, *b5, *b6;
  const int* act;
  const float *cutg, *latg;
  float* out_lat;
};
__global__ __launch_bounds__(256) void k_mlp(MlpArgs A) {
  __shared__ char sm[61440];
  char* Xa = sm;                 // 32 x 384B (192 cols)
  char* Xb = sm + 12288;         // 32 x 256B (128 cols)
  char* Xe = sm + 20480;         // 32 x 256B (eoh)
  char* W0 = sm + 28672;         // 16KB window
  char* W1 = sm + 45056;         // 16KB window
  const int tid = threadIdx.x;
  const int lane = tid & 63, w = tid >> 6;
  const int wr = w >> 1, wc = w & 1;
  const int lane15 = lane & 15, g16 = lane >> 4;
  const int e32 = blockIdx.x * 32;
  const f32x4 vzero = {0.f, 0.f, 0.f, 0.f};

  auto stage_w = [&](const ushort* Wt, int K2, int t2, char* dst) {
#pragma unroll
    for (int it = 0; it < 4; ++it) {
      int q = tid + it * 256;
      int c = q >> 3, ch = (q & 7) ^ (c & 7);
      gload16((const char*)Wt + (size_t)c * K2 + t2 * 128 + ch * 16,
              dst + (w + it * 4) * 1024);
    }
  };
  // initial X staging: m1in -> Xa (768 chunks), eoh(m2in[:,128:]) -> Xe (512 chunks)
  {
#pragma unroll
    for (int it = 0; it < 3; ++it) {
      int q = tid + it * 256;
      int r = q / 24, c24 = q - r * 24;
      int t2 = c24 >> 3, ch = (c24 & 7) ^ (r & 7);
      gload16((const char*)A.m1in + (size_t)(e32 + r) * 384 + t2 * 128 + ch * 16,
              Xa + (w + it * 4) * 1024);
    }
#pragma unroll
    for (int it = 0; it < 2; ++it) {
      int q = tid + it * 256;
      int r = q >> 4, c16 = q & 15;
      int t2 = c16 >> 3, ch = (c16 & 7) ^ (r & 7);
      gload16((const char*)A.m2in + (size_t)(e32 + r) * 512 + 256 + t2 * 128 + ch * 16,
              Xe + (w + it * 4) * 1024);
    }
  }
  stage_w(A.Wt1, 384, 0, W0);
  __syncthreads();

  f32x4 acc[4];
#pragma unroll
  for (int n = 0; n < 4; ++n) acc[n] = vzero;

  auto compute = [&](const char* xin, int xstride, int t2loc, const char* wl) {
#pragma unroll
    for (int s = 0; s < 2; ++s) {
      int row = wr * 16 + lane15;
      bf16x8 a = *(const bf16x8*)(xin + row * xstride + t2loc * 128 + (((s * 4 + g16) ^ (row & 7)) << 4));
#pragma unroll
      for (int n = 0; n < 4; ++n) {
        int cB = wc * 64 + n * 16 + lane15;
        bf16x8 b = *(const bf16x8*)(wl + cB * 128 + (((s * 4 + g16) ^ (cB & 7)) << 4));
        acc[n] = __builtin_amdgcn_mfma_f32_16x16x32_bf16(a, b, acc[n], 0, 0, 0);
      }
    }
  };
  auto epi_x = [&](const float* bias, char* xout, int xstride, bool dosilu) {
#pragma unroll
    for (int n = 0; n < 4; ++n) {
      int c = wc * 64 + n * 16 + lane15;
      float bv = bias[c];
      int ch = (n * 16 + lane15) >> 3;
#pragma unroll
      for (int j = 0; j < 4; ++j) {
        int row = wr * 16 + g16 * 4 + j;
        float v = acc[n][j] + bv;
        if (dosilu) v = v / (1.f + __expf(-v));
        *(ushort*)(xout + row * xstride + wc * 128 + ((ch ^ (row & 7)) << 4) + ((lane15 & 7) << 1)) = f2bf(v);
      }
      acc[n] = vzero;
    }
  };

  // L1 (K=192, Xa->Xb, silu)
  stage_w(A.Wt1, 384, 1, W1); compute(Xa, 384, 0, W0); __syncthreads();
  stage_w(A.Wt1, 384, 2, W0); compute(Xa, 384, 1, W1); __syncthreads();
  stage_w(A.Wt2, 256, 0, W1); compute(Xa, 384, 2, W0); epi_x(A.b1, Xb, 256, true); __syncthreads();
  // L2 (K=128, Xb->Xa, silu)
  stage_w(A.Wt2, 256, 1, W0); compute(Xb, 256, 0, W1); __syncthreads();
  stage_w(A.Wt3, 256, 0, W1); compute(Xb, 256, 1, W0); epi_x(A.b2, Xa, 384, true); __syncthreads();
  // L3 (K=128, Xa->Xb, no silu)
  stage_w(A.Wt3, 256, 1, W0); compute(Xa, 384, 0, W1); __syncthreads();
  stage_w(A.Wt4, 512, 0, W1); compute(Xa, 384, 1, W0); epi_x(A.b3, Xb, 256, false); __syncthreads();
  // L4 (K=256: Xb win0,1 + Xe win0,1 -> Xa, silu)
  stage_w(A.Wt4, 512, 1, W0); compute(Xb, 256, 0, W1); __syncthreads();
  stage_w(A.Wt4, 512, 2, W1); compute(Xb, 256, 1, W0); __syncthreads();
  stage_w(A.Wt4, 512, 3, W0); compute(Xe, 256, 0, W1); __syncthreads();
  stage_w(A.Wt5, 256, 0, W1); compute(Xe, 256, 1, W0); epi_x(A.b4, Xa, 384, true); __syncthreads();
  // L5 (K=128, Xa->Xb, silu)
  stage_w(A.Wt5, 256, 1, W0); compute(Xa, 384, 0, W1); __syncthreads();
  stage_w(A.Wt6, 256, 0, W1); compute(Xa, 384, 1, W0); epi_x(A.b5, Xb, 256, true); __syncthreads();
  // L6 (K=128, Xb -> out_lat via latent update)
  stage_w(A.Wt6, 256, 1, W0); compute(Xb, 256, 0, W1); __syncthreads();
  compute(Xb, 256, 1, W0);
#pragma unroll
  for (int n = 0; n < 4; ++n) {
    int c = wc * 64 + n * 16 + lane15;
    float bv = A.b6[c];
#pragma unroll
    for (int j = 0; j < 4; ++j) {
      int row = wr * 16 + g16 * 4 + j;
      int er = e32 + row;
      int ae = A.act[er];
      float v = acc[n][j] + bv;
      A.out_lat[(size_t)ae * 128 + c] = C_NEW * A.cutg[ae] * v + C_OLD * A.latg[(size_t)ae * 128 + c];
    }
  }
}

// ---------------- post-MoE fused with final combine: 8 edges/block ----------------
__global__ __launch_bounds__(256) void k_postf(
    const ushort* __restrict__ moeout,
    const float* __restrict__ D1g, const float* __restrict__ D2g,
    const float* __restrict__ latg, const int* __restrict__ act,
    const float* __restrict__ P1, const float* __restrict__ P2,
    const ushort* __restrict__ wbuf, const float* __restrict__ beg,
    const float* __restrict__ lng, const float* __restrict__ lnb,
    const ushort* __restrict__ tbufp, const float* __restrict__ efg,
    ushort* __restrict__ m1in, float* __restrict__ out_edge) {
  __shared__ float SM[8384];
  float* sP1 = SM;
  float* sP2 = SM + 1024;
  float* be_s = SM + 1280;
  float* lng_s = SM + 1392;
  float* lnb_s = SM + 1520;
  float* sO   = SM + 1648;
  float* sLat = SM + 3440;
  float* sWv  = SM + 4464;
  float* sU1  = SM + 5360;
  float* sU2  = SM + 6128;
  float* sSg  = SM + 6768;
  float* sD1  = SM + 7152;
  float* sD2  = SM + 7248;
  float* sMu  = SM + 7472;
  float* sRs  = SM + 7480;
  float* sTv  = SM + 7488;  // 8*112
  const int t = threadIdx.x;
  const int e8 = blockIdx.x * 8;

  for (int q = t; q < 368; q += 256) {
    if (q < 112) be_s[q] = beg[q];
    else if (q < 240) lng_s[q - 112] = lng[q - 112];
    else lnb_s[q - 240] = lnb[q - 240];
  }
  for (int q = t; q < 896; q += 256) {
    int e = q / 112, d = q - e * 112;
    sTv[q] = bf2f(tbufp[(size_t)(e8 + e) * 128 + d]) * T_SCALE;
  }
  for (int q = t; q < 1024; q += 256) {
    int d = q >> 5, c = q & 31;
    sP1[d * 32 + ((((c >> 2) + d) & 7) << 2) + (c & 3)] = P1[c * 32 + d];
  }
  {
    int d = t >> 4, c = t & 15;
    if (t < 256) sP2[d * 16 + ((((c >> 2) + d) & 3) << 2) + (c & 3)] = P2[c * 16 + d];
  }
  {
    int e = t >> 5, kq = t & 31;
    if (kq < 28) {
      uintx4 raw = *(const uintx4*)(moeout + (size_t)(e8 + e) * 288 + 64 + kq * 8);
      float* d = sO + e * 224 + kq * 8;
#pragma unroll
      for (int j = 0; j < 4; ++j) {
        uint u = raw[j];
        d[2 * j] = bf2f((ushort)(u & 0xFFFF));
        d[2 * j + 1] = bf2f((ushort)(u >> 16));
      }
    }
  }
  {
    int e = t >> 5, i = t & 31;
    int ae = act[e8 + e];
    ((float4v*)(sLat + e * 128))[i] = ((const float4v*)(latg + (size_t)ae * 128))[i];
  }
  {
    int e = t >> 4, kq = t & 15;
    if (e < 8 && kq < 14) {
      uintx4 raw = *(const uintx4*)(wbuf + (size_t)(e8 + e) * 128 + kq * 8);
      float* d = sWv + e * 112 + kq * 8;
#pragma unroll
      for (int j = 0; j < 4; ++j) {
        uint u = raw[j];
        d[2 * j] = bf2f((ushort)(u & 0xFFFF));
        d[2 * j + 1] = bf2f((ushort)(u >> 16));
      }
    }
  }
  for (int q = t; q < 512; q += 256) {
    int e = q >> 6, i = q & 63;
    if (i < 9) sD1[e * 12 + i] = D1g[(size_t)(e8 + e) * 9 + i];
    else if (i < 34) sD2[e * 28 + (i - 9)] = D2g[(size_t)(e8 + e) * 25 + (i - 9)];
  }
  __syncthreads();

  for (int q = t; q < 384; q += 256) {
    int e = q / 48, c = q - (q / 48) * 48;
    sSg[e * 48 + c] = 1.f / (1.f + __expf(-sO[e * 224 + c]));
  }
  __syncthreads();

  for (int q = t; q < 768; q += 256) {
    int e = q / 96, r = q - (q / 96) * 96;
    int m = r >> 5, c = r & 31;
    const float* o = sO + e * 224;
    const float* d1 = sD1 + e * 12;
    float v = d1[m] * o[144 + c] + d1[3 + m] * o[48 + c] + d1[6 + m] * o[96 + c];
    sU1[e * 96 + m * 32 + c] = v * sSg[e * 48 + c];
  }
  for (int q = t; q < 640; q += 256) {
    int e = q / 80, r = q - (q / 80) * 80;
    int m = r >> 4, c = r & 15;
    const float* o = sO + e * 224;
    const float* d2 = sD2 + e * 28;
    float v = d2[m] * o[208 + c] + d2[5 + m] * o[176 + c] + d2[10 + m] * o[80 + c] +
              d2[15 + m] * o[128 + c] + d2[20 + m] * o[192 + c];
    sU2[e * 80 + m * 16 + c] = v * sSg[e * 48 + 32 + c];
  }
  {
    int eg = t >> 5, l = t & 31;
    const float* lt = sLat + eg * 128;
    float v0 = lt[l], v1 = lt[l + 32], v2 = lt[l + 64], v3 = lt[l + 96];
    float sum = v0 + v1 + v2 + v3;
    float sq = v0 * v0 + v1 * v1 + v2 * v2 + v3 * v3;
#pragma unroll
    for (int m = 16; m > 0; m >>= 1) {
      sum += __shfl_xor(sum, m);
      sq += __shfl_xor(sq, m);
    }
    if (l == 0) {
      float mu = sum * (1.f / 128.f);
      float var = sq * (1.f / 128.f) - mu * mu;
      sMu[eg] = mu;
      sRs[eg] = rsqrtf(var + 1e-5f);
    }
  }
  __syncthreads();

  for (int q = t; q < 768; q += 256) {
    int e = q / 96, r = q - (q / 96) * 96;
    int m = r >> 5, d = r & 31;
    const float* u = sU1 + e * 96 + m * 32;
    float acc = 0.f;
#pragma unroll
    for (int cq = 0; cq < 8; ++cq) {
      float4v p = *(const float4v*)(sP1 + d * 32 + (((cq + d) & 7) << 2));
      float4v uu = *(const float4v*)(u + cq * 4);
      acc += p[0] * uu[0] + p[1] * uu[1] + p[2] * uu[2] + p[3] * uu[3];
    }
    int pos = 64 + d * 3 + m;
    float nv = acc * (sWv[e * 112 + 64 + d] + be_s[64 + d]);
    out_edge[(size_t)(e8 + e) * 240 + pos] =
        (C_OLD * efg[(size_t)(e8 + e) * 240 + pos] + C_NEW * nv) * (1.f + sTv[e * 112 + 64 + d]);
  }
  for (int q = t; q < 640; q += 256) {
    int e = q / 80, r = q - (q / 80) * 80;
    int m = r >> 4, d = r & 15;
    const float* u = sU2 + e * 80 + m * 16;
    float acc = 0.f;
#pragma unroll
    for (int cq = 0; cq < 4; ++cq) {
      float4v p = *(const float4v*)(sP2 + d * 16 + (((cq + d) & 3) << 2));
      float4v uu = *(const float4v*)(u + cq * 4);
      acc += p[0] * uu[0] + p[1] * uu[1] + p[2] * uu[2] + p[3] * uu[3];
    }
    int pos = 160 + d * 5 + m;
    float nv = acc * (sWv[e * 112 + 96 + d] + be_s[96 + d]);
    out_edge[(size_t)(e8 + e) * 240 + pos] =
        (C_OLD * efg[(size_t)(e8 + e) * 240 + pos] + C_NEW * nv) * (1.f + sTv[e * 112 + 96 + d]);
  }
  for (int q = t; q < 512; q += 256) {
    int e = q >> 6, d = q & 63;
    float sp = bf2f(m1in[(size_t)(e8 + e) * 192 + 128 + d]);
    float nv = sp * (sWv[e * 112 + d] + be_s[d]);
    out_edge[(size_t)(e8 + e) * 240 + d] =
        (C_OLD * efg[(size_t)(e8 + e) * 240 + d] + C_NEW * nv) * (1.f + sTv[e * 112 + d]);
  }
  for (int q = t; q < 512; q += 256) {
    int e = q >> 6, i2 = q & 63;
    const float* lt = sLat + e * 128;
    float mu = sMu[e], rs = sRs[e];
    int i = 2 * i2;
    float l0 = (lt[i] - mu) * rs * lng_s[i] + lnb_s[i];
    float l1 = (lt[i + 1] - mu) * rs * lng_s[i + 1] + lnb_s[i + 1];
    ((uint*)m1in)[(size_t)(e8 + e) * 96 + i2] = (uint)f2bf(l0) | ((uint)f2bf(l1) << 16);
  }
}

extern "C" void kernel_launch(void* const* d_in, const int* in_sizes, int n_in,
                              void* d_out, int out_size, void* d_ws, size_t ws_size,
                              hipStream_t stream) {
  const float* latents = (const float*)d_in[0];
  const float* node_f  = (const float*)d_in[1];
  const float* edge_f  = (const float*)d_in[3];
  const float* cutoff  = (const float*)d_in[5];
  const float* eoh     = (const float*)d_in[6];
  const float* D1      = (const float*)d_in[7];
  const float* D2      = (const float*)d_in[8];
  const float* mg      = (const float*)d_in[9];
  const int*   eidx    = (const int*)d_in[10];
  const int*   act     = (const int*)d_in[11];
  const float* Wg      = (const float*)d_in[12];
  const float* W0      = (const float*)d_in[13];
  const float* W1r     = (const float*)d_in[14];
  const float* W1i     = (const float*)d_in[15];
  const float* W2r     = (const float*)d_in[16];
  const float* W2i     = (const float*)d_in[17];
  const float* P0      = (const float*)d_in[18];
  const float* b0      = (const float*)d_in[19];
  const float* P1      = (const float*)d_in[20];
  const float* P2      = (const float*)d_in[21];
  const float* We      = (const float*)d_in[22];
  const float* be      = (const float*)d_in[23];
  const float* lng     = (const float*)d_in[24];
  const float* lnb     = (const float*)d_in[25];
  const float* M1W0_   = (const float*)d_in[26];
  const float* M1b0_   = (const float*)d_in[27];
  const float* M1W1_   = (const float*)d_in[28];
  const float* M1b1_   = (const float*)d_in[29];
  const float* M1W2_   = (const float*)d_in[30];
  const float* M1b2_   = (const float*)d_in[31];
  const float* M2W0_   = (const float*)d_in[32];
  const float* M2b0_   = (const float*)d_in[33];
  const float* M2W1_   = (const float*)d_in[34];
  const float* M2b1_   = (const float*)d_in[35];
  const float* M2W2_   = (const float*)d_in[36];
  const float* M2b2_   = (const float*)d_in[37];
  const float* T0      = (const float*)d_in[38];
  const float* T1      = (const float*)d_in[39];
  const float* T2      = (const float*)d_in[40];

  float* out_edge = (float*)d_out;
  float* out_lat  = out_edge + (size_t)EDGES * 240;
  float* out_d1   = out_lat + (size_t)EDGES * 128;
  float* out_d2   = out_d1 + (size_t)EDGES * 9;

  char* ws = (char*)d_ws;
  size_t off = 0;
  auto alloc = [&](size_t bytes) -> char* {
    char* p = ws + off;
    off += (bytes + 255) & ~size_t(255);
    return p;
  };
  ushort* f_all  = (ushort*)alloc((size_t)EDGES * 832 * 2);
  float*  gfb    = (float*) alloc((size_t)EDGES * 12 * 4);
  ushort* moeout = (ushort*)alloc((size_t)EDGES * 288 * 2);
  ushort* m2in   = (ushort*)alloc((size_t)EDGES * 256 * 2);
  ushort* latbf  = (ushort*)alloc((size_t)EDGES * 128 * 2);
  ushort* wbuf   = (ushort*)alloc((size_t)EDGES * 128 * 2);
  ushort* B0t    = (ushort*)alloc(160 * 3456 * 2);
  ushort* B1t    = (ushort*)alloc(96 * 2880 * 2);
  ushort* B2t    = (ushort*)alloc(32 * 1152 * 2);
  ushort* Wt1    = (ushort*)alloc(128 * 192 * 2);
  ushort* Wt2    = (ushort*)alloc(128 * 128 * 2);
  ushort* Wt3    = (ushort*)alloc(128 * 128 * 2);
  ushort* Wt4    = (ushort*)alloc(128 * 256 * 2);
  ushort* Wt5    = (ushort*)alloc(128 * 128 * 2);
  ushort* Wt6    = (ushort*)alloc(128 * 128 * 2);
  ushort* Wet    = (ushort*)alloc(128 * 128 * 2);
  ushort* Ttb    = (ushort*)alloc(128 * 128 * 2);
  ushort* P0t    = (ushort*)alloc(64 * 64 * 2);

  ushort* m1in = f_all;   // E*192 overlay (dead after MoE GEMMs)
  ushort* tbuf = latbf;   // reused after We-GEMM

  hipMemcpyAsync(out_d1, (const void*)D1, (size_t)EDGES * 9 * 4, hipMemcpyDeviceToDevice, stream);
  hipMemcpyAsync(out_d2, (const void*)D2, (size_t)EDGES * 25 * 4, hipMemcpyDeviceToDevice, stream);

  if (ws_size < off) return;

  k_pack_b0<<<2160, 256, 0, stream>>>(W0, B0t);
  k_pack_b1<<<1080, 256, 0, stream>>>(W1r, W1i, B1t);
  k_pack_b2<<<144, 256, 0, stream>>>(W2r, W2i, B2t);
  PackPtrs pp = {M1W0_, M1W1_, M1W2_, M2W0_, M2W1_, M2W2_, We, T0, T1, T2, P0,
                 Wt1, Wt2, Wt3, Wt4, Wt5, Wt6, Wet, Ttb, P0t};
  k_pack_small<<<624, 256, 0, stream>>>(pp);

  k_prep<<<EDGES / 4, 256, 0, stream>>>(node_f, edge_f, D1, D2, mg, Wg, latents, eoh,
                                        eidx, act, f_all, gfb, latbf, m2in);

  // MoE GEMMs; moe0 also emits scs = silu(o0[:,:64]) into m2in[:,0:64]
  k_gemm<3456, 6, 9, 160, 0, 832, false, 2>
      <<<1024, 256, 0, stream>>>(f_all, B0t, gfb, nullptr, moeout, 288, 0, m2in);
  k_gemm<2880, 5, 9, 96, 384, 832, false, 0>
      <<<1024, 256, 0, stream>>>(f_all, B1t, gfb, nullptr, moeout, 288, 160, nullptr);
  k_gemm<1152, 2, 9, 32, 704, 832, false, 0>
      <<<1024, 256, 0, stream>>>(f_all, B2t, gfb, nullptr, moeout, 288, 256, nullptr);

  // lat @ We ; eoh @ T^T
  k_gemm<128, 1, 1, 128, 0, 128, false, 0>
      <<<1024, 256, 0, stream>>>(latbf, Wet, nullptr, nullptr, wbuf, 128, 0, nullptr);
  k_gemm<128, 1, 1, 128, 128, 256, false, 0>
      <<<1024, 256, 0, stream>>>(m2in, Ttb, nullptr, nullptr, tbuf, 128, 0, nullptr);

  // sps = scs @ P0 + b0 -> m1in cols 128..191
  k_gemm<64, 1, 1, 64, 0, 256, true, 0>
      <<<1024, 256, 0, stream>>>(m2in, P0t, nullptr, b0, m1in, 192, 128, nullptr);

  // fused post + final combine: writes out_edge directly and m1in LN cols
  k_postf<<<EDGES / 8, 256, 0, stream>>>(moeout, D1, D2, latents, act, P1, P2,
                                         wbuf, be, lng, lnb, tbuf, edge_f, m1in, out_edge);

  // fused 6-layer MLP chain (final layer fuses latent update into out_lat)
  MlpArgs ma = {m1in, m2in, Wt1, Wt2, Wt3, Wt4, Wt5, Wt6,
                M1b0_, M1b1_, M1b2_, M2b0_, M2b1_, M2b2_,
                act, cutoff, latents, out_lat};
  k_mlp<<<EDGES / 32, 256, 0, stream>>>(ma);
}